// Round 5
// baseline (35568.494 us; speedup 1.0000x reference)
//
#include <hip/hip_runtime.h>
#include <hip/hip_cooperative_groups.h>
#include <math.h>
#include <limits.h>

namespace cg = cooperative_groups;

#define B32 32
#define KD 1024
#define HID 1024
#define VOC 32000
#define NL 3
#define TN 128
#define BKC 32
#define ASTR 36
#define WSTR 68
#define GEMM_THREADS 128
#define KS_GRU 4
#define KSF 8          // GRU k-split (fast path)

typedef __attribute__((ext_vector_type(8))) short bf16x8;
typedef __attribute__((ext_vector_type(8))) unsigned short u16x8;
typedef __attribute__((ext_vector_type(16))) float f32x16;

__device__ __forceinline__ float sigmoidf_(float x) { return 1.0f / (1.0f + expf(-x)); }

__device__ __forceinline__ unsigned short f2bf(float f) {
    unsigned u = __float_as_uint(f);
    u = u + 0x7fffu + ((u >> 16) & 1u);
    return (unsigned short)(u >> 16);
}
__device__ __forceinline__ float bf2f(unsigned short h) {
    return __uint_as_float(((unsigned)h) << 16);
}
__device__ __forceinline__ f32x16 MF(bf16x8 a, bf16x8 b, f32x16 c) {
    return __builtin_amdgcn_mfma_f32_32x32x16_bf16(a, b, c, 0, 0, 0);
}

// ---------------- one-time pack: fp32 row-major [ntiles*32][1024] -> hi/lo fragment-packed
__global__ __launch_bounds__(256)
void pack_w(const float* __restrict__ src, unsigned short* __restrict__ hi,
            unsigned short* __restrict__ lo, long ntiles)
{
    long tid = (long)blockIdx.x * 256 + threadIdx.x;
    long total = ntiles * 4096;
    if (tid >= total) return;
    long tile = tid >> 12;
    int r = (int)(tid & 4095);
    int k8 = r >> 5, c = r & 31;
    const float* s = src + ((size_t)tile * 32 + c) * KD + k8 * 8;
    float4 f0 = ((const float4*)s)[0];
    float4 f1 = ((const float4*)s)[1];
    float ff[8] = {f0.x, f0.y, f0.z, f0.w, f1.x, f1.y, f1.z, f1.w};
    u16x8 h, l;
#pragma unroll
    for (int j = 0; j < 8; ++j) {
        unsigned short hh = f2bf(ff[j]);
        h[j] = hh;
        l[j] = f2bf(ff[j] - bf2f(hh));
    }
    size_t o = ((size_t)tile << 15) + (size_t)k8 * 256 + (size_t)c * 8;
    *(u16x8*)(hi + o) = h;
    *(u16x8*)(lo + o) = l;
}

// ================== PERSISTENT COOPERATIVE DECODER ==================
// 256 blocks x 512 threads (8 waves), 1 block/CU. Per step:
//   3x GRU phase (blocks=(jt,ks8), waves 0-5 = panels, fused last-arrival gates)
//   1x logits phase (blocks 0-249, 4 tiles x 2 k-halves) + u64 atomicMax argmax
// 4 grid.sync()/step. Math bit-identical to the R4 multi-kernel path.
__global__ __launch_bounds__(512)
void decoder_persist(const float* __restrict__ emb,
                     const unsigned short* __restrict__ wihh, const unsigned short* __restrict__ wihl,
                     const unsigned short* __restrict__ whhh, const unsigned short* __restrict__ whhl,
                     const unsigned short* __restrict__ fcwh, const unsigned short* __restrict__ fcwl,
                     const float* __restrict__ bihA, const float* __restrict__ bhhA,
                     const float* __restrict__ fcb,
                     unsigned short* __restrict__ hAh, unsigned short* __restrict__ hAl,
                     unsigned short* __restrict__ hBh, unsigned short* __restrict__ hBl,
                     float* __restrict__ G, unsigned int* __restrict__ cnt,
                     unsigned long long* __restrict__ amaxbuf,
                     float* __restrict__ out, int T)
{
    cg::grid_group grid = cg::this_grid();
    const int bid = blockIdx.x;
    const int tid = threadIdx.x;
    const int w = tid >> 6, lane = tid & 63;
    __shared__ float red[4][B32][32];
    __shared__ float bvalS[4][B32];
    __shared__ int   bidxS[4][B32];
    __shared__ int sflag;

    const int jt = bid >> 3, ks = bid & 7;

    for (int t = 0; t < T; ++t) {
        unsigned long long* rbuf = amaxbuf + (size_t)((t + 1) & 1) * B32;
        unsigned long long* wbuf = amaxbuf + (size_t)(t & 1) * B32;
        unsigned short* ch = (t & 1) ? hBh : hAh;
        unsigned short* cl = (t & 1) ? hBl : hAl;
        unsigned short* nh = (t & 1) ? hAh : hBh;
        unsigned short* nl = (t & 1) ? hAl : hBl;

        // ---------- GRU layers ----------
        for (int l = 0; l < NL; ++l) {
            if (l == 0 && bid == 0 && w == 7 && lane < B32) wbuf[lane] = 0ull;  // reset argmax buf
            if (w < 6) {
                const int gate = (w < 3) ? w : w - 3;
                const bool isX = (w < 3);
                const size_t lofs = (size_t)l * 3 * KD * KD + (((size_t)(gate * 32 + jt)) << 15);
                const unsigned short* Wh = (isX ? wihh : whhh) + lofs;
                const unsigned short* Wl = (isX ? wihl : whhl) + lofs;
                const int kbase = ks * 8;
                f32x16 acc = {0,0,0,0,0,0,0,0,0,0,0,0,0,0,0,0};
                if (isX && l == 0) {
                    // gather A-fragments directly from emb (bit-identical to packed path)
                    unsigned long long key = rbuf[lane & 31];
                    int tok = (int)(0xFFFFFFFFu - (unsigned)(key & 0xFFFFFFFFull));
                    const float* er = emb + (size_t)tok * KD + (size_t)(lane >> 5) * 8;
#pragma unroll
                    for (int i = 0; i < 8; ++i) {
                        int k16 = kbase + i;
                        const float* s = er + (size_t)k16 * 16;
                        float4 f0 = ((const float4*)s)[0];
                        float4 f1 = ((const float4*)s)[1];
                        float ff[8] = {f0.x, f0.y, f0.z, f0.w, f1.x, f1.y, f1.z, f1.w};
                        bf16x8 ah, al;
#pragma unroll
                        for (int j = 0; j < 8; ++j) {
                            unsigned short hh = f2bf(ff[j]);
                            ah[j] = (short)hh;
                            al[j] = (short)f2bf(ff[j] - bf2f(hh));
                        }
                        size_t o = (size_t)k16 * 512 + (size_t)lane * 8;
                        bf16x8 wh = *(const bf16x8*)(Wh + o), wl2 = *(const bf16x8*)(Wl + o);
                        acc = MF(ah, wh, acc);
                        acc = MF(al, wh, acc);
                        acc = MF(ah, wl2, acc);
                    }
                } else {
                    const unsigned short* Ah = isX ? (nh + (size_t)(l - 1) * B32 * KD)
                                                   : (ch + (size_t)l * B32 * KD);
                    const unsigned short* Al = isX ? (nl + (size_t)(l - 1) * B32 * KD)
                                                   : (cl + (size_t)l * B32 * KD);
#pragma unroll
                    for (int i = 0; i < 8; ++i) {
                        size_t o = (size_t)(kbase + i) * 512 + (size_t)lane * 8;
                        bf16x8 ah = *(const bf16x8*)(Ah + o), al = *(const bf16x8*)(Al + o);
                        bf16x8 wh = *(const bf16x8*)(Wh + o), wl2 = *(const bf16x8*)(Wl + o);
                        acc = MF(ah, wh, acc);
                        acc = MF(al, wh, acc);
                        acc = MF(ah, wl2, acc);
                    }
                }
                const int kg = lane >> 5, c = lane & 31;
                float* Gb = G + ((size_t)(jt * KSF + ks) * 6 + w) * 1024;
#pragma unroll
                for (int r = 0; r < 16; ++r) {
                    int b = (r & 3) + 8 * (r >> 2) + 4 * kg;
                    Gb[b * 32 + c] = acc[r];
                }
            }
            __syncthreads();
            if (tid == 0) {
                __threadfence();
                unsigned old = atomicAdd(&cnt[jt], 1u);
                int fl = (old == KSF - 1) ? 1 : 0;
                sflag = fl;
                if (fl) atomicExch(&cnt[jt], 0u);
            }
            __syncthreads();
            if (sflag) {
                __threadfence();
                const float* bih = bihA + (size_t)l * 3 * KD;
                const float* bhh = bhhA + (size_t)l * 3 * KD;
                const unsigned short* hch = ch + (size_t)l * B32 * KD;
                const unsigned short* hcl = cl + (size_t)l * B32 * KD;
                unsigned short* hnh = nh + (size_t)l * B32 * KD;
                unsigned short* hnl = nl + (size_t)l * B32 * KD;
                for (int idx = tid; idx < B32 * 32; idx += 512) {
                    int b = idx >> 5, c2 = idx & 31;
                    int j = jt * 32 + c2;
                    float s0 = 0, s1 = 0, s2 = 0, s3 = 0, s4 = 0, s5 = 0;
#pragma unroll
                    for (int k2 = 0; k2 < KSF; ++k2) {
                        const float* base = G + ((size_t)(jt * KSF + k2) * 6) * 1024 + b * 32 + c2;
                        s0 += base[0];    s1 += base[1024]; s2 += base[2048];
                        s3 += base[3072]; s4 += base[4096]; s5 += base[5120];
                    }
                    float rg = sigmoidf_(s0 + bih[j] + s3 + bhh[j]);
                    float zg = sigmoidf_(s1 + bih[KD + j] + s4 + bhh[KD + j]);
                    float ng = tanhf(s2 + bih[2 * KD + j] + rg * (s5 + bhh[2 * KD + j]));
                    size_t hp = (size_t)(j >> 3) * 256 + (size_t)b * 8 + (j & 7);
                    float hold = bf2f(hch[hp]) + bf2f(hcl[hp]);
                    float hnew = (1.0f - zg) * ng + zg * hold;
                    unsigned short hh = f2bf(hnew);
                    hnh[hp] = hh;
                    hnl[hp] = f2bf(hnew - bf2f(hh));
                }
                __threadfence();
            }
            grid.sync();
        }

        // ---------- logits + argmax ----------
        if (bid < 250) {
            const unsigned short* xh = nh + (size_t)2 * B32 * KD;
            const unsigned short* xl = nl + (size_t)2 * B32 * KD;
            const int tw = w & 3, kh = w >> 2;
            const int tile = bid * 4 + tw;
            const int n0 = tile * 32;
            const unsigned short* Whp = fcwh + ((size_t)tile << 15);
            const unsigned short* Wlp = fcwl + ((size_t)tile << 15);
            const size_t lo8 = (size_t)lane * 8;
            const int kbase = kh * 32;

            f32x16 acc = {0,0,0,0,0,0,0,0,0,0,0,0,0,0,0,0};
            size_t o0 = (size_t)kbase * 512 + lo8;
            size_t o1 = (size_t)(kbase + 1) * 512 + lo8;
            bf16x8 ah0 = *(const bf16x8*)(xh + o0),  al0 = *(const bf16x8*)(xl + o0);
            bf16x8 wh0 = *(const bf16x8*)(Whp + o0), wl0 = *(const bf16x8*)(Wlp + o0);
            bf16x8 ah1 = *(const bf16x8*)(xh + o1),  al1 = *(const bf16x8*)(xl + o1);
            bf16x8 wh1 = *(const bf16x8*)(Whp + o1), wl1 = *(const bf16x8*)(Wlp + o1);

            for (int i = 0; i < 32; ++i) {
                size_t on = (size_t)(kbase + ((i + 2) & 31)) * 512 + lo8;
                bf16x8 ahn = *(const bf16x8*)(xh + on),  aln = *(const bf16x8*)(xl + on);
                bf16x8 whn = *(const bf16x8*)(Whp + on), wln = *(const bf16x8*)(Wlp + on);
                acc = MF(ah0, wh0, acc);
                acc = MF(al0, wh0, acc);
                acc = MF(ah0, wl0, acc);
                ah0 = ah1; al0 = al1; wh0 = wh1; wl0 = wl1;
                ah1 = ahn; al1 = aln; wh1 = whn; wl1 = wln;
            }

            const int kg = lane >> 5, col = lane & 31;
            if (kh == 1) {
#pragma unroll
                for (int r = 0; r < 16; ++r) {
                    int b = (r & 3) + 8 * (r >> 2) + 4 * kg;
                    red[tw][b][col] = acc[r];
                }
            }
            __syncthreads();
            if (kh == 0) {
                const float bb = fcb[n0 + col];
#pragma unroll
                for (int r = 0; r < 16; ++r) {
                    int b = (r & 3) + 8 * (r >> 2) + 4 * kg;
                    float v = acc[r] + red[tw][b][col] + bb;
                    out[((size_t)b * T + t) * VOC + n0 + col] = v;
                    float mv = v; int mi = n0 + col;
#pragma unroll
                    for (int m = 1; m < 32; m <<= 1) {
                        float ov = __shfl_xor(mv, m);
                        int   oi = __shfl_xor(mi, m);
                        if (ov > mv || (ov == mv && oi < mi)) { mv = ov; mi = oi; }
                    }
                    if (col == 0) { bvalS[tw][b] = mv; bidxS[tw][b] = mi; }
                }
            }
            __syncthreads();
            if (tid < B32) {
                int b = tid;
                float mv = bvalS[0][b]; int mi = bidxS[0][b];
#pragma unroll
                for (int q = 1; q < 4; ++q) {
                    float v = bvalS[q][b]; int ii = bidxS[q][b];
                    if (v > mv || (v == mv && ii < mi)) { mv = v; mi = ii; }
                }
                unsigned u = __float_as_uint(mv);
                u = (u >> 31) ? ~u : (u | 0x80000000u);
                unsigned long long key =
                    ((unsigned long long)u << 32) | (unsigned long long)(0xFFFFFFFFu - (unsigned)mi);
                atomicMax(wbuf + b, key);
            }
        }
        grid.sync();
    }
}

// ================== R4 multi-kernel fallback ==================
__global__ __launch_bounds__(256)
void token_pack2(const float* __restrict__ emb,
                 const unsigned long long* __restrict__ rbuf,
                 unsigned long long* __restrict__ wbuf,
                 unsigned short* __restrict__ xhi, unsigned short* __restrict__ xlo,
                 int do_amax)
{
    const int tid = threadIdx.x;
    if (blockIdx.x == 0 && tid < B32) wbuf[tid] = 0ull;
    const int row = blockIdx.x * 2 + (tid >> 7);
    const int c = tid & 127;
    int tok = 0;
    if (do_amax) {
        unsigned long long key = rbuf[row];
        tok = (int)(0xFFFFFFFFu - (unsigned)(key & 0xFFFFFFFFull));
    }
    const float* s = emb + (size_t)tok * KD + c * 8;
    float4 f0 = ((const float4*)s)[0];
    float4 f1 = ((const float4*)s)[1];
    float ff[8] = {f0.x, f0.y, f0.z, f0.w, f1.x, f1.y, f1.z, f1.w};
    u16x8 h, l;
#pragma unroll
    for (int j = 0; j < 8; ++j) {
        unsigned short hh = f2bf(ff[j]);
        h[j] = hh;
        l[j] = f2bf(ff[j] - bf2f(hh));
    }
    size_t o = (size_t)c * 256 + (size_t)row * 8;
    *(u16x8*)(xhi + o) = h;
    *(u16x8*)(xlo + o) = l;
}

__global__ __launch_bounds__(384)
void gru_fused(const unsigned short* __restrict__ xh, const unsigned short* __restrict__ xl,
               const unsigned short* __restrict__ hch, const unsigned short* __restrict__ hcl,
               unsigned short* __restrict__ hnh, unsigned short* __restrict__ hnl,
               const unsigned short* __restrict__ wihh, const unsigned short* __restrict__ wihl,
               const unsigned short* __restrict__ whhh, const unsigned short* __restrict__ whhl,
               const float* __restrict__ bih, const float* __restrict__ bhh,
               float* __restrict__ G, unsigned int* __restrict__ cnt)
{
    __shared__ int sflag;
    const int bid = blockIdx.x;
    const int jt = bid >> 3, ks = bid & 7;
    const int tid = threadIdx.x;
    const int w = tid >> 6, lane = tid & 63;
    const int gate = (w < 3) ? w : w - 3;
    const unsigned short* Ah = (w < 3) ? xh : hch;
    const unsigned short* Al = (w < 3) ? xl : hcl;
    const size_t woff = ((size_t)(gate * 32 + jt)) << 15;
    const unsigned short* Wh = ((w < 3) ? wihh : whhh) + woff;
    const unsigned short* Wl = ((w < 3) ? wihl : whhl) + woff;
    const size_t lo8 = (size_t)lane * 8;
    const int kbase = ks * 8;

    f32x16 acc = {0,0,0,0,0,0,0,0,0,0,0,0,0,0,0,0};
    size_t o0 = (size_t)kbase * 512 + lo8;
    bf16x8 ah0 = *(const bf16x8*)(Ah + o0), al0 = *(const bf16x8*)(Al + o0);
    bf16x8 wh0 = *(const bf16x8*)(Wh + o0), wl0 = *(const bf16x8*)(Wl + o0);
#pragma unroll
    for (int i = 0; i < 8; ++i) {
        size_t on = (size_t)(kbase + ((i + 1) & 7)) * 512 + lo8;
        bf16x8 ahn = *(const bf16x8*)(Ah + on), aln = *(const bf16x8*)(Al + on);
        bf16x8 whn = *(const bf16x8*)(Wh + on), wln = *(const bf16x8*)(Wl + on);
        acc = MF(ah0, wh0, acc);
        acc = MF(al0, wh0, acc);
        acc = MF(ah0, wl0, acc);
        ah0 = ahn; al0 = aln; wh0 = whn; wl0 = wln;
    }

    const int kg = lane >> 5, c = lane & 31;
    float* Gb = G + ((size_t)(jt * KSF + ks) * 6 + w) * 1024;
#pragma unroll
    for (int r = 0; r < 16; ++r) {
        int b = (r & 3) + 8 * (r >> 2) + 4 * kg;
        Gb[b * 32 + c] = acc[r];
    }
    __syncthreads();
    if (tid == 0) {
        __threadfence();
        unsigned old = atomicAdd(&cnt[jt], 1u);
        sflag = (old == KSF - 1) ? 1 : 0;
        if (sflag) cnt[jt] = 0u;
    }
    __syncthreads();
    if (sflag) {
        __threadfence();
        for (int idx = tid; idx < B32 * 32; idx += 384) {
            int b = idx >> 5, c2 = idx & 31;
            int j = jt * 32 + c2;
            float s0 = 0, s1 = 0, s2 = 0, s3 = 0, s4 = 0, s5 = 0;
#pragma unroll
            for (int k2 = 0; k2 < KSF; ++k2) {
                const float* base = G + ((size_t)(jt * KSF + k2) * 6) * 1024 + b * 32 + c2;
                s0 += base[0];    s1 += base[1024]; s2 += base[2048];
                s3 += base[3072]; s4 += base[4096]; s5 += base[5120];
            }
            float rg = sigmoidf_(s0 + bih[j] + s3 + bhh[j]);
            float zg = sigmoidf_(s1 + bih[KD + j] + s4 + bhh[KD + j]);
            float ng = tanhf(s2 + bih[2 * KD + j] + rg * (s5 + bhh[2 * KD + j]));
            size_t hp = (size_t)(j >> 3) * 256 + (size_t)b * 8 + (j & 7);
            float hold = bf2f(hch[hp]) + bf2f(hcl[hp]);
            float hnew = (1.0f - zg) * ng + zg * hold;
            unsigned short hh = f2bf(hnew);
            hnh[hp] = hh;
            hnl[hp] = f2bf(hnew - bf2f(hh));
        }
    }
}

__global__ __launch_bounds__(512)
void logits3(const unsigned short* __restrict__ xh, const unsigned short* __restrict__ xl,
             const unsigned short* __restrict__ wh, const unsigned short* __restrict__ wl,
             const float* __restrict__ bias, float* __restrict__ out, int t, int T,
             unsigned long long* __restrict__ amax)
{
    __shared__ float red[4][B32][32];
    __shared__ float bval[4][B32];
    __shared__ int   bidx[4][B32];
    const int tid = threadIdx.x;
    const int w = tid >> 6, lane = tid & 63;
    const int tw = w & 3, kh = w >> 2;
    const int tile = blockIdx.x * 4 + tw;
    const int n0 = tile * 32;
    const unsigned short* Wh = wh + ((size_t)tile << 15);
    const unsigned short* Wl = wl + ((size_t)tile << 15);
    const size_t lo8 = (size_t)lane * 8;
    const int kbase = kh * 32;

    f32x16 acc = {0,0,0,0,0,0,0,0,0,0,0,0,0,0,0,0};
    size_t o0 = (size_t)kbase * 512 + lo8;
    size_t o1 = (size_t)(kbase + 1) * 512 + lo8;
    bf16x8 ah0 = *(const bf16x8*)(xh + o0), al0 = *(const bf16x8*)(xl + o0);
    bf16x8 wh0 = *(const bf16x8*)(Wh + o0), wl0 = *(const bf16x8*)(Wl + o0);
    bf16x8 ah1 = *(const bf16x8*)(xh + o1), al1 = *(const bf16x8*)(xl + o1);
    bf16x8 wh1 = *(const bf16x8*)(Wh + o1), wl1 = *(const bf16x8*)(Wl + o1);

    for (int i = 0; i < 32; ++i) {
        size_t on = (size_t)(kbase + ((i + 2) & 31)) * 512 + lo8;
        bf16x8 ahn = *(const bf16x8*)(xh + on), aln = *(const bf16x8*)(xl + on);
        bf16x8 whn = *(const bf16x8*)(Wh + on), wln = *(const bf16x8*)(Wl + on);
        acc = MF(ah0, wh0, acc);
        acc = MF(al0, wh0, acc);
        acc = MF(ah0, wl0, acc);
        ah0 = ah1; al0 = al1; wh0 = wh1; wl0 = wl1;
        ah1 = ahn; al1 = aln; wh1 = whn; wl1 = wln;
    }

    const int kg = lane >> 5, col = lane & 31;
    if (kh == 1) {
#pragma unroll
        for (int r = 0; r < 16; ++r) {
            int b = (r & 3) + 8 * (r >> 2) + 4 * kg;
            red[tw][b][col] = acc[r];
        }
    }
    __syncthreads();
    if (kh == 0) {
        const float bb = bias[n0 + col];
#pragma unroll
        for (int r = 0; r < 16; ++r) {
            int b = (r & 3) + 8 * (r >> 2) + 4 * kg;
            float v = acc[r] + red[tw][b][col] + bb;
            out[((size_t)b * T + t) * VOC + n0 + col] = v;
            float mv = v; int mi = n0 + col;
#pragma unroll
            for (int m = 1; m < 32; m <<= 1) {
                float ov = __shfl_xor(mv, m);
                int   oi = __shfl_xor(mi, m);
                if (ov > mv || (ov == mv && oi < mi)) { mv = ov; mi = oi; }
            }
            if (col == 0) { bval[tw][b] = mv; bidx[tw][b] = mi; }
        }
    }
    __syncthreads();
    if (tid < B32) {
        int b = tid;
        float mv = bval[0][b]; int mi = bidx[0][b];
#pragma unroll
        for (int q = 1; q < 4; ++q) {
            float v = bval[q][b]; int ii = bidx[q][b];
            if (v > mv || (v == mv && ii < mi)) { mv = v; mi = ii; }
        }
        unsigned u = __float_as_uint(mv);
        u = (u >> 31) ? ~u : (u | 0x80000000u);
        unsigned long long key =
            ((unsigned long long)u << 32) | (unsigned long long)(0xFFFFFFFFu - (unsigned)mi);
        atomicMax(amax + b, key);
    }
}

// ================= fp32 fallback (round-1, proven) =================
__global__ __launch_bounds__(GEMM_THREADS)
void gemm_k1024(const float* __restrict__ Ax, const float* __restrict__ Ah,
                const float* __restrict__ emb, const int* __restrict__ tokens, int gather0,
                const float* __restrict__ Wx, const float* __restrict__ Wh,
                const float* __restrict__ bias,
                float* __restrict__ C, int N, int KS)
{
    __shared__ float As[BKC * ASTR];
    __shared__ float Ws[2 * BKC * WSTR];
    const int tid = threadIdx.x;
    const int sel = blockIdx.y;
    const int ks  = blockIdx.x % KS;
    const int nt  = blockIdx.x / KS;
    const int n0  = nt * TN;
    const int klen = KD / KS;
    const int k0 = ks * klen;
    const float* A = sel ? Ah : Ax;
    const float* W = sel ? Wh : Wx;
    const bool gather = (sel == 0) && (gather0 != 0);

    const int tb = tid & 7;
    const int tn = tid >> 3;
    const int s_kq = tid & 7;
    const int s_r  = tid >> 3;

    const float* arow0;
    const float* arow1;
    if (gather) {
        arow0 = emb + (size_t)tokens[s_r] * KD;
        arow1 = emb + (size_t)tokens[s_r + 16] * KD;
    } else {
        arow0 = A + (size_t)s_r * KD;
        arow1 = A + (size_t)(s_r + 16) * KD;
    }
    const float* wrow = W + (size_t)(n0 + s_r) * KD;

    float acc[4][8];
#pragma unroll
    for (int i = 0; i < 4; ++i)
#pragma unroll
        for (int j = 0; j < 8; ++j) acc[i][j] = 0.0f;

    for (int kc = 0; kc < klen; kc += BKC) {
        const int kb = k0 + kc + s_kq * 4;
        float4 a0 = *(const float4*)(arow0 + kb);
        float4 a1 = *(const float4*)(arow1 + kb);
        float4 wv[8];
#pragma unroll
        for (int hh = 0; hh < 8; ++hh)
            wv[hh] = *(const float4*)(wrow + (size_t)hh * 16 * KD + kb);

        __syncthreads();
#pragma unroll
        for (int j = 0; j < 4; ++j) {
            As[(s_kq * 4 + j) * ASTR + s_r]      = ((const float*)&a0)[j];
            As[(s_kq * 4 + j) * ASTR + s_r + 16] = ((const float*)&a1)[j];
        }
#pragma unroll
        for (int hh = 0; hh < 8; ++hh) {
            int row = s_r + hh * 16;
            int half = row >> 6;
            int c = row & 63;
            float* wbase = &Ws[half * BKC * WSTR];
#pragma unroll
            for (int j = 0; j < 4; ++j)
                wbase[(s_kq * 4 + j) * WSTR + c] = ((const float*)&wv[hh])[j];
        }
        __syncthreads();

#pragma unroll
        for (int kk = 0; kk < BKC; ++kk) {
            float4 av = *(const float4*)&As[kk * ASTR + 4 * tb];
            float4 w0 = *(const float4*)&Ws[kk * WSTR + 4 * tn];
            float4 w1 = *(const float4*)&Ws[BKC * WSTR + kk * WSTR + 4 * tn];
#pragma unroll
            for (int i = 0; i < 4; ++i) {
                float a = ((const float*)&av)[i];
                acc[i][0] += a * w0.x; acc[i][1] += a * w0.y;
                acc[i][2] += a * w0.z; acc[i][3] += a * w0.w;
                acc[i][4] += a * w1.x; acc[i][5] += a * w1.y;
                acc[i][6] += a * w1.z; acc[i][7] += a * w1.w;
            }
        }
    }

    const int slice = sel * KS + ks;
    float* Cb = C + (size_t)slice * B32 * N;
    float4 bA = make_float4(0.f, 0.f, 0.f, 0.f), bB = bA;
    if (bias != nullptr && ks == 0) {
        bA = *(const float4*)&bias[n0 + 4 * tn];
        bB = *(const float4*)&bias[n0 + 64 + 4 * tn];
    }
#pragma unroll
    for (int i = 0; i < 4; ++i) {
        int b = 4 * tb + i;
        float4 vA = make_float4(acc[i][0] + bA.x, acc[i][1] + bA.y, acc[i][2] + bA.z, acc[i][3] + bA.w);
        float4 vB = make_float4(acc[i][4] + bB.x, acc[i][5] + bB.y, acc[i][6] + bB.z, acc[i][7] + bB.w);
        *(float4*)&Cb[(size_t)b * N + n0 + 4 * tn]       = vA;
        *(float4*)&Cb[(size_t)b * N + n0 + 64 + 4 * tn]  = vB;
    }
}

__global__ __launch_bounds__(256)
void gru_gates(const float* __restrict__ G,
               const float* __restrict__ bih, const float* __restrict__ bhh,
               float* __restrict__ hl)
{
    int idx = blockIdx.x * 256 + threadIdx.x;
    int b = idx >> 10, j = idx & 1023;
    float xr = 0, xz = 0, xn = 0, hr = 0, hz = 0, hn = 0;
#pragma unroll
    for (int ks = 0; ks < KS_GRU; ++ks) {
        const float* gx = G + ((size_t)ks * B32 + b) * 3072;
        const float* gh = G + ((size_t)(KS_GRU + ks) * B32 + b) * 3072;
        xr += gx[j];        xz += gx[1024 + j];  xn += gx[2048 + j];
        hr += gh[j];        hz += gh[1024 + j];  hn += gh[2048 + j];
    }
    float r = sigmoidf_(xr + bih[j] + hr + bhh[j]);
    float z = sigmoidf_(xz + bih[1024 + j] + hz + bhh[1024 + j]);
    float n = tanhf(xn + bih[2048 + j] + r * (hn + bhh[2048 + j]));
    float ho = hl[idx];
    hl[idx] = (1.0f - z) * n + z * ho;
}

__global__ __launch_bounds__(GEMM_THREADS)
void logits_kernel(const float* __restrict__ x,
                   const float* __restrict__ W, const float* __restrict__ bias,
                   float* __restrict__ out, int t, int T,
                   float* __restrict__ pval, int* __restrict__ pidx)
{
    __shared__ float As[BKC * ASTR];
    __shared__ float Ws[2 * BKC * WSTR];
    __shared__ float rval[B32 * 16];
    __shared__ int   ridx[B32 * 16];
    const int tid = threadIdx.x;
    const int n0 = blockIdx.x * TN;
    const int tb = tid & 7;
    const int tn = tid >> 3;
    const int s_kq = tid & 7;
    const int s_r  = tid >> 3;

    const float* arow0 = x + (size_t)s_r * KD;
    const float* arow1 = x + (size_t)(s_r + 16) * KD;
    const float* wrow  = W + (size_t)(n0 + s_r) * KD;

    float acc[4][8];
#pragma unroll
    for (int i = 0; i < 4; ++i)
#pragma unroll
        for (int j = 0; j < 8; ++j) acc[i][j] = 0.0f;

    for (int kc = 0; kc < KD; kc += BKC) {
        const int kb = kc + s_kq * 4;
        float4 a0 = *(const float4*)(arow0 + kb);
        float4 a1 = *(const float4*)(arow1 + kb);
        float4 wv[8];
#pragma unroll
        for (int hh = 0; hh < 8; ++hh)
            wv[hh] = *(const float4*)(wrow + (size_t)hh * 16 * KD + kb);

        __syncthreads();
#pragma unroll
        for (int j = 0; j < 4; ++j) {
            As[(s_kq * 4 + j) * ASTR + s_r]      = ((const float*)&a0)[j];
            As[(s_kq * 4 + j) * ASTR + s_r + 16] = ((const float*)&a1)[j];
        }
#pragma unroll
        for (int hh = 0; hh < 8; ++hh) {
            int row = s_r + hh * 16;
            int half = row >> 6;
            int c = row & 63;
            float* wbase = &Ws[half * BKC * WSTR];
#pragma unroll
            for (int j = 0; j < 4; ++j)
                wbase[(s_kq * 4 + j) * WSTR + c] = ((const float*)&wv[hh])[j];
        }
        __syncthreads();

#pragma unroll
        for (int kk = 0; kk < BKC; ++kk) {
            float4 av = *(const float4*)&As[kk * ASTR + 4 * tb];
            float4 w0 = *(const float4*)&Ws[kk * WSTR + 4 * tn];
            float4 w1 = *(const float4*)&Ws[BKC * WSTR + kk * WSTR + 4 * tn];
#pragma unroll
            for (int i = 0; i < 4; ++i) {
                float a = ((const float*)&av)[i];
                acc[i][0] += a * w0.x; acc[i][1] += a * w0.y;
                acc[i][2] += a * w0.z; acc[i][3] += a * w0.w;
                acc[i][4] += a * w1.x; acc[i][5] += a * w1.y;
                acc[i][6] += a * w1.z; acc[i][7] += a * w1.w;
            }
        }
    }

    float4 bA = *(const float4*)&bias[n0 + 4 * tn];
    float4 bB = *(const float4*)&bias[n0 + 64 + 4 * tn];

    float bestv[4]; int besti[4];
#pragma unroll
    for (int i = 0; i < 4; ++i) { bestv[i] = -INFINITY; besti[i] = INT_MAX; }

#pragma unroll
    for (int i = 0; i < 4; ++i) {
        int b = 4 * tb + i;
        float* orow = out + ((size_t)b * T + t) * VOC;
        float4 vA = make_float4(acc[i][0] + bA.x, acc[i][1] + bA.y, acc[i][2] + bA.z, acc[i][3] + bA.w);
        float4 vB = make_float4(acc[i][4] + bB.x, acc[i][5] + bB.y, acc[i][6] + bB.z, acc[i][7] + bB.w);
        *(float4*)&orow[n0 + 4 * tn]      = vA;
        *(float4*)&orow[n0 + 64 + 4 * tn] = vB;
#pragma unroll
        for (int j = 0; j < 4; ++j) {
            float v = ((const float*)&vA)[j]; int c = n0 + 4 * tn + j;
            if (v > bestv[i] || (v == bestv[i] && c < besti[i])) { bestv[i] = v; besti[i] = c; }
        }
#pragma unroll
        for (int j = 0; j < 4; ++j) {
            float v = ((const float*)&vB)[j]; int c = n0 + 64 + 4 * tn + j;
            if (v > bestv[i] || (v == bestv[i] && c < besti[i])) { bestv[i] = v; besti[i] = c; }
        }
    }
#pragma unroll
    for (int i = 0; i < 4; ++i) {
        rval[(4 * tb + i) * 16 + tn] = bestv[i];
        ridx[(4 * tb + i) * 16 + tn] = besti[i];
    }
    __syncthreads();
    if (tid < B32) {
        int b = tid;
        float bv = -INFINITY; int bi = INT_MAX;
        for (int q = 0; q < 16; ++q) {
            float v = rval[b * 16 + q]; int ii = ridx[b * 16 + q];
            if (v > bv || (v == bv && ii < bi)) { bv = v; bi = ii; }
        }
        pval[(size_t)blockIdx.x * B32 + b] = bv;
        pidx[(size_t)blockIdx.x * B32 + b] = bi;
    }
}

__global__ __launch_bounds__(256)
void amax_final(const float* __restrict__ pval, const int* __restrict__ pidx,
                int nblk, int* __restrict__ tokens)
{
    int tid = threadIdx.x;
    int b = tid >> 3, l8 = tid & 7;
    float bv = -INFINITY; int bi = INT_MAX;
    for (int q = l8; q < nblk; q += 8) {
        float v = pval[(size_t)q * B32 + b]; int ii = pidx[(size_t)q * B32 + b];
        if (v > bv || (v == bv && ii < bi)) { bv = v; bi = ii; }
    }
#pragma unroll
    for (int off = 1; off < 8; off <<= 1) {
        float ov = __shfl_xor(bv, off);
        int   oi = __shfl_xor(bi, off);
        if (ov > bv || (ov == bv && oi < bi)) { bv = ov; bi = oi; }
    }
    if (l8 == 0) tokens[b] = bi;
}

// ---------------- host ----------------
extern "C" void kernel_launch(void* const* d_in, const int* in_sizes, int n_in,
                              void* d_out, int out_size, void* d_ws, size_t ws_size,
                              hipStream_t stream)
{
    const float* z    = (const float*)d_in[0];
    const float* emb  = (const float*)d_in[1];
    const float* wlat = (const float*)d_in[2];
    const float* blat = (const float*)d_in[3];
    const float* wih  = (const float*)d_in[4];
    const float* whh  = (const float*)d_in[5];
    const float* bih  = (const float*)d_in[6];
    const float* bhh  = (const float*)d_in[7];
    const float* fcw  = (const float*)d_in[8];
    const float* fcb  = (const float*)d_in[9];
    float* out = (float*)d_out;
    const int T = out_size / (B32 * VOC);   // 128

    const size_t NEED = 214500000;
    if (ws_size >= NEED) {
        char* p = (char*)d_ws;
        auto take = [&](size_t bytes) { char* r = p; p += (bytes + 255) & ~(size_t)255; return r; };
        unsigned short* fcwPh = (unsigned short*)take((size_t)VOC * KD * 2);
        unsigned short* fcwPl = (unsigned short*)take((size_t)VOC * KD * 2);
        unsigned short* wihPh = (unsigned short*)take((size_t)NL * 3 * KD * KD * 2);
        unsigned short* wihPl = (unsigned short*)take((size_t)NL * 3 * KD * KD * 2);
        unsigned short* whhPh = (unsigned short*)take((size_t)NL * 3 * KD * KD * 2);
        unsigned short* whhPl = (unsigned short*)take((size_t)NL * 3 * KD * KD * 2);
        unsigned short* hAh   = (unsigned short*)take((size_t)NL * B32 * KD * 2);
        unsigned short* hAl   = (unsigned short*)take((size_t)NL * B32 * KD * 2);
        unsigned short* hBh   = (unsigned short*)take((size_t)NL * B32 * KD * 2);
        unsigned short* hBl   = (unsigned short*)take((size_t)NL * B32 * KD * 2);
        unsigned short* xPh   = (unsigned short*)take((size_t)B32 * KD * 2);
        unsigned short* xPl   = (unsigned short*)take((size_t)B32 * KD * 2);
        float* G   = (float*)take((size_t)32 * KSF * 6 * 1024 * 4);
        float* h32 = (float*)take((size_t)B32 * NL * KD * 4);
        unsigned long long* amaxbuf = (unsigned long long*)take(2 * B32 * 8);
        unsigned int* cnt = (unsigned int*)take(32 * 4);

        hipMemsetAsync(cnt, 0, 32 * sizeof(unsigned int), stream);
        hipMemsetAsync(amaxbuf, 0x00, B32 * 8, stream);          // wbuf(t=0)
        hipMemsetAsync(amaxbuf + B32, 0xFF, B32 * 8, stream);    // rbuf(t=0) -> token 0

        // one-time weight packing (split hi/lo + MFMA fragment order)
        {
            long nt_fc = VOC / 32;
            long nt_g  = (long)NL * 3 * KD / 32;
            pack_w<<<(unsigned)((nt_fc * 4096 + 255) / 256), 256, 0, stream>>>(fcw, fcwPh, fcwPl, nt_fc);
            pack_w<<<(unsigned)((nt_g * 4096 + 255) / 256), 256, 0, stream>>>(wih, wihPh, wihPl, nt_g);
            pack_w<<<(unsigned)((nt_g * 4096 + 255) / 256), 256, 0, stream>>>(whh, whhPh, whhPl, nt_g);
        }

        // hidden init (fp32), then pack the 3 [32x1024] planes into hA
        gemm_k1024<<<dim3(NL * KD / TN, 1), GEMM_THREADS, 0, stream>>>(
            z, nullptr, nullptr, nullptr, 0, wlat, nullptr, blat, h32, NL * KD, 1);
        pack_w<<<(unsigned)((3L * 4096 + 255) / 256), 256, 0, stream>>>(h32, hAh, hAl, 3);

        // ---- persistent cooperative decoder ----
        int T_ = T;
        void* kargs[] = {
            (void*)&emb,
            (void*)&wihPh, (void*)&wihPl, (void*)&whhPh, (void*)&whhPl,
            (void*)&fcwPh, (void*)&fcwPl,
            (void*)&bih, (void*)&bhh, (void*)&fcb,
            (void*)&hAh, (void*)&hAl, (void*)&hBh, (void*)&hBl,
            (void*)&G, (void*)&cnt, (void*)&amaxbuf,
            (void*)&out, (void*)&T_
        };
        hipError_t ce = hipLaunchCooperativeKernel((void*)decoder_persist,
                                                   dim3(256), dim3(512), kargs, 0, stream);
        if (ce != hipSuccess) {
            (void)hipGetLastError();
            // ---- fallback: R4 multi-kernel path (bit-identical results) ----
            for (int t = 0; t < T; ++t) {
                unsigned long long* rbuf = amaxbuf + (size_t)((t + 1) & 1) * B32;
                unsigned long long* wbuf = amaxbuf + (size_t)(t & 1) * B32;
                unsigned short* ch = (t & 1) ? hBh : hAh;
                unsigned short* cl = (t & 1) ? hBl : hAl;
                unsigned short* nh = (t & 1) ? hAh : hBh;
                unsigned short* nl = (t & 1) ? hAl : hBl;

                token_pack2<<<16, 256, 0, stream>>>(emb, rbuf, wbuf, xPh, xPl, t > 0 ? 1 : 0);
                for (int l = 0; l < NL; ++l) {
                    const unsigned short* xh = (l == 0) ? xPh : nh + (size_t)(l - 1) * B32 * KD;
                    const unsigned short* xl = (l == 0) ? xPl : nl + (size_t)(l - 1) * B32 * KD;
                    gru_fused<<<32 * KSF, 384, 0, stream>>>(
                        xh, xl,
                        ch + (size_t)l * B32 * KD, cl + (size_t)l * B32 * KD,
                        nh + (size_t)l * B32 * KD, nl + (size_t)l * B32 * KD,
                        wihPh + (size_t)l * 3 * KD * KD, wihPl + (size_t)l * 3 * KD * KD,
                        whhPh + (size_t)l * 3 * KD * KD, whhPl + (size_t)l * 3 * KD * KD,
                        bih + (size_t)l * 3 * KD, bhh + (size_t)l * 3 * KD,
                        G, cnt);
                }
                logits3<<<VOC / 128, 512, 0, stream>>>(
                    nh + (size_t)2 * B32 * KD, nl + (size_t)2 * B32 * KD,
                    fcwPh, fcwPl, fcb, out, t, T, wbuf);
            }
        }
    } else {
        // fallback: round-1 fp32 path
        float* h      = (float*)d_ws;
        float* G      = h + (size_t)B32 * NL * HID;
        float* pval   = G + (size_t)2 * KS_GRU * B32 * NL * HID;
        int*   pidx   = (int*)(pval + (VOC / TN) * B32);
        int*   tokens = (int*)(pidx + (VOC / TN) * B32);

        hipMemsetAsync(tokens, 0, B32 * sizeof(int), stream);

        gemm_k1024<<<dim3(NL * HID / TN, 1), GEMM_THREADS, 0, stream>>>(
            z, nullptr, nullptr, nullptr, 0, wlat, nullptr, blat, h, NL * HID, 1);

        for (int t = 0; t < T; ++t) {
            for (int l = 0; l < NL; ++l) {
                const float* xA = (l == 0) ? nullptr : (h + (size_t)(l - 1) * B32 * HID);
                dim3 gg((NL * HID / TN) * KS_GRU, 2);
                gemm_k1024<<<gg, GEMM_THREADS, 0, stream>>>(
                    xA, h + (size_t)l * B32 * HID, emb, tokens, (l == 0) ? 1 : 0,
                    wih + (size_t)l * NL * HID * KD, whh + (size_t)l * NL * HID * KD,
                    nullptr, G, NL * HID, KS_GRU);
                gru_gates<<<B32 * HID / 256, 256, 0, stream>>>(
                    G, bih + (size_t)l * NL * HID, bhh + (size_t)l * NL * HID,
                    h + (size_t)l * B32 * HID);
            }
            logits_kernel<<<VOC / TN, GEMM_THREADS, 0, stream>>>(
                h + (size_t)2 * B32 * HID, fcw, fcb, out, t, T, pval, pidx);
            amax_final<<<1, 256, 0, stream>>>(pval, pidx, VOC / TN, tokens);
        }
    }
}

// Round 6
// 33526.871 us; speedup vs baseline: 1.0609x; 1.0609x over previous
//
#include <hip/hip_runtime.h>
#include <math.h>
#include <limits.h>

#define B32 32
#define KD 1024
#define HID 1024
#define VOC 32000
#define NL 3
#define TN 128
#define BKC 32
#define ASTR 36
#define WSTR 68
#define GEMM_THREADS 128
#define KS_GRU 4
#define KSF 16         // GRU k-split (fast path)
#define CANDMAX 64

typedef __attribute__((ext_vector_type(8))) short bf16x8;
typedef __attribute__((ext_vector_type(8))) unsigned short u16x8;
typedef __attribute__((ext_vector_type(16))) float f32x16;

__device__ __forceinline__ float sigmoidf_(float x) { return 1.0f / (1.0f + expf(-x)); }

__device__ __forceinline__ unsigned short f2bf(float f) {
    unsigned u = __float_as_uint(f);
    u = u + 0x7fffu + ((u >> 16) & 1u);
    return (unsigned short)(u >> 16);
}
__device__ __forceinline__ float bf2f(unsigned short h) {
    return __uint_as_float(((unsigned)h) << 16);
}
__device__ __forceinline__ f32x16 MF(bf16x8 a, bf16x8 b, f32x16 c) {
    return __builtin_amdgcn_mfma_f32_32x32x16_bf16(a, b, c, 0, 0, 0);
}

// ---------------- one-time pack: fp32 [ntiles*32][1024] -> fragment-packed hi (+optional lo)
__global__ __launch_bounds__(256)
void pack_w(const float* __restrict__ src, unsigned short* __restrict__ hi,
            unsigned short* __restrict__ lo, long ntiles)
{
    long tid = (long)blockIdx.x * 256 + threadIdx.x;
    long total = ntiles * 4096;
    if (tid >= total) return;
    long tile = tid >> 12;
    int r = (int)(tid & 4095);
    int k8 = r >> 5, c = r & 31;
    const float* s = src + ((size_t)tile * 32 + c) * KD + k8 * 8;
    float4 f0 = ((const float4*)s)[0];
    float4 f1 = ((const float4*)s)[1];
    float ff[8] = {f0.x, f0.y, f0.z, f0.w, f1.x, f1.y, f1.z, f1.w};
    u16x8 h, l;
#pragma unroll
    for (int j = 0; j < 8; ++j) {
        unsigned short hh = f2bf(ff[j]);
        h[j] = hh;
        l[j] = f2bf(ff[j] - bf2f(hh));
    }
    size_t o = ((size_t)tile << 15) + (size_t)k8 * 256 + (size_t)c * 8;
    *(u16x8*)(hi + o) = h;
    if (lo) *(u16x8*)(lo + o) = l;
}

// ---------------- one-time: max column norm of fcw (rows of fcw are logit columns)
__global__ __launch_bounds__(256)
void wnorm_k(const float* __restrict__ fcw, unsigned* __restrict__ wn)
{
    const int tid = threadIdx.x;
    const int r = blockIdx.x * 64 + (tid >> 2);
    const int q = tid & 3;
    const float* row = fcw + (size_t)r * KD + q * 256;
    float s = 0.f;
#pragma unroll 8
    for (int i = 0; i < 64; ++i) {
        float4 v = ((const float4*)row)[i];
        s += v.x * v.x + v.y * v.y + v.z * v.z + v.w * v.w;
    }
    s += __shfl_xor(s, 1);
    s += __shfl_xor(s, 2);
    if (q == 0) atomicMax(wn, __float_as_uint(sqrtf(s)));
}

// ---------------- fused GRU layer: split-K(16) GEMM + last-block gates ----------
// grid 512 x 384 thr (6 waves = 6 panels). jt = bid>>4, ks = bid&15.
// l==0: A-fragments gathered+split directly from emb via tokens[].
__global__ __launch_bounds__(384, 3)
void gru_fused2(const int* __restrict__ tokens, const float* __restrict__ emb, int gather,
                const unsigned short* __restrict__ xh, const unsigned short* __restrict__ xl,
                const unsigned short* __restrict__ hch, const unsigned short* __restrict__ hcl,
                unsigned short* __restrict__ hnh, unsigned short* __restrict__ hnl,
                const unsigned short* __restrict__ wihh, const unsigned short* __restrict__ wihl,
                const unsigned short* __restrict__ whhh, const unsigned short* __restrict__ whhl,
                const float* __restrict__ bih, const float* __restrict__ bhh,
                float* __restrict__ G, unsigned int* __restrict__ cnt)
{
    __shared__ int sflag;
    const int bid = blockIdx.x;
    const int jt = bid >> 4, ks = bid & 15;
    const int tid = threadIdx.x;
    const int w = tid >> 6, lane = tid & 63;
    const int kbase = ks * 4;            // K16-steps: 4 per split

    if (w < 6) {
        const int gate = (w < 3) ? w : w - 3;
        const bool isX = (w < 3);
        const size_t woff = ((size_t)(gate * 32 + jt)) << 15;
        const unsigned short* Wh = (isX ? wihh : whhh) + woff;
        const unsigned short* Wl = (isX ? wihl : whhl) + woff;
        const size_t lo8 = (size_t)lane * 8;

        f32x16 acc = {0,0,0,0,0,0,0,0,0,0,0,0,0,0,0,0};
        if (isX && gather) {
            int tok = tokens[lane & 31];
            const float* er = emb + (size_t)tok * KD + (size_t)(lane >> 5) * 8;
#pragma unroll
            for (int i = 0; i < 4; ++i) {
                int k16 = kbase + i;
                const float* s = er + (size_t)k16 * 16;
                float4 f0 = ((const float4*)s)[0];
                float4 f1 = ((const float4*)s)[1];
                float ff[8] = {f0.x, f0.y, f0.z, f0.w, f1.x, f1.y, f1.z, f1.w};
                bf16x8 ah, al;
#pragma unroll
                for (int j = 0; j < 8; ++j) {
                    unsigned short hh = f2bf(ff[j]);
                    ah[j] = (short)hh;
                    al[j] = (short)f2bf(ff[j] - bf2f(hh));
                }
                size_t o = (size_t)k16 * 512 + lo8;
                bf16x8 wh = *(const bf16x8*)(Wh + o), wl2 = *(const bf16x8*)(Wl + o);
                acc = MF(ah, wh, acc);
                acc = MF(al, wh, acc);
                acc = MF(ah, wl2, acc);
            }
        } else {
            const unsigned short* Ah = isX ? xh : hch;
            const unsigned short* Al = isX ? xl : hcl;
#pragma unroll
            for (int i = 0; i < 4; ++i) {
                size_t o = (size_t)(kbase + i) * 512 + lo8;
                bf16x8 ah = *(const bf16x8*)(Ah + o), al = *(const bf16x8*)(Al + o);
                bf16x8 wh = *(const bf16x8*)(Wh + o), wl2 = *(const bf16x8*)(Wl + o);
                acc = MF(ah, wh, acc);
                acc = MF(al, wh, acc);
                acc = MF(ah, wl2, acc);
            }
        }
        const int kg = lane >> 5, c = lane & 31;
        float* Gb = G + ((size_t)(jt * KSF + ks) * 6 + w) * 1024;
#pragma unroll
        for (int r = 0; r < 16; ++r) {
            int b = (r & 3) + 8 * (r >> 2) + 4 * kg;
            Gb[b * 32 + c] = acc[r];
        }
    }
    __syncthreads();
    if (tid == 0) {
        __threadfence();
        unsigned old = atomicAdd(&cnt[jt], 1u);
        sflag = (old == KSF - 1) ? 1 : 0;
        if (sflag) cnt[jt] = 0u;
    }
    __syncthreads();
    if (sflag) {
        __threadfence();
        for (int idx = tid; idx < B32 * 32; idx += 384) {
            int b = idx >> 5, c2 = idx & 31;
            int j = jt * 32 + c2;
            float s0 = 0, s1 = 0, s2 = 0, s3 = 0, s4 = 0, s5 = 0;
#pragma unroll
            for (int k2 = 0; k2 < KSF; ++k2) {
                const float* base = G + ((size_t)(jt * KSF + k2) * 6) * 1024 + b * 32 + c2;
                s0 += base[0];    s1 += base[1024]; s2 += base[2048];
                s3 += base[3072]; s4 += base[4096]; s5 += base[5120];
            }
            float rg = sigmoidf_(s0 + bih[j] + s3 + bhh[j]);
            float zg = sigmoidf_(s1 + bih[KD + j] + s4 + bhh[KD + j]);
            float ng = tanhf(s2 + bih[2 * KD + j] + rg * (s5 + bhh[2 * KD + j]));
            size_t hp = (size_t)(j >> 3) * 256 + (size_t)b * 8 + (j & 7);
            float hold = bf2f(hch[hp]) + bf2f(hcl[hp]);
            float hnew = (1.0f - zg) * ng + zg * hold;
            unsigned short hh = f2bf(hnew);
            hnh[hp] = hh;
            hnl[hp] = f2bf(hnew - bf2f(hh));
        }
    }
}

// ---------------- logits: hi-only W, 500 blocks x 512 thr (2 tiles x 4 k-quarters) ----------
__global__ __launch_bounds__(512, 4)
void logits4(const unsigned short* __restrict__ xh, const unsigned short* __restrict__ xl,
             const unsigned short* __restrict__ wh,
             const float* __restrict__ bias, float* __restrict__ out, int t, int T,
             unsigned long long* __restrict__ amax)
{
    __shared__ float red[2][3][B32][32];
    __shared__ float bvalS[2][B32];
    __shared__ int   bidxS[2][B32];
    const int tid = threadIdx.x;
    const int w = tid >> 6, lane = tid & 63;
    const int tw = w & 1, kq = w >> 1;
    const int tile = blockIdx.x * 2 + tw;
    const int n0 = tile * 32;
    const unsigned short* Wt = wh + ((size_t)tile << 15);
    const size_t lo8 = (size_t)lane * 8;
    const int kbase = kq * 16;

    f32x16 acc = {0,0,0,0,0,0,0,0,0,0,0,0,0,0,0,0};
    size_t o0 = (size_t)kbase * 512 + lo8;
    size_t o1 = o0 + 512;
    bf16x8 ah0 = *(const bf16x8*)(xh + o0), al0 = *(const bf16x8*)(xl + o0);
    bf16x8 wv0 = *(const bf16x8*)(Wt + o0);
    bf16x8 ah1 = *(const bf16x8*)(xh + o1), al1 = *(const bf16x8*)(xl + o1);
    bf16x8 wv1 = *(const bf16x8*)(Wt + o1);

    for (int i = 0; i < 16; ++i) {
        size_t on = (size_t)(kbase + ((i + 2) & 15)) * 512 + lo8;
        bf16x8 ahn = *(const bf16x8*)(xh + on), aln = *(const bf16x8*)(xl + on);
        bf16x8 wvn = *(const bf16x8*)(Wt + on);
        acc = MF(ah0, wv0, acc);
        acc = MF(al0, wv0, acc);
        ah0 = ah1; al0 = al1; wv0 = wv1;
        ah1 = ahn; al1 = aln; wv1 = wvn;
    }

    const int kg = lane >> 5, col = lane & 31;
    if (kq > 0) {
#pragma unroll
        for (int r = 0; r < 16; ++r) {
            int b = (r & 3) + 8 * (r >> 2) + 4 * kg;
            red[tw][kq - 1][b][col] = acc[r];
        }
    }
    __syncthreads();
    if (kq == 0) {
        const float bb = bias[n0 + col];
#pragma unroll
        for (int r = 0; r < 16; ++r) {
            int b = (r & 3) + 8 * (r >> 2) + 4 * kg;
            float v = acc[r] + red[tw][0][b][col] + red[tw][1][b][col] + red[tw][2][b][col] + bb;
            out[((size_t)b * T + t) * VOC + n0 + col] = v;
            float mv = v; int mi = n0 + col;
#pragma unroll
            for (int m = 1; m < 32; m <<= 1) {
                float ov = __shfl_xor(mv, m);
                int   oi = __shfl_xor(mi, m);
                if (ov > mv || (ov == mv && oi < mi)) { mv = ov; mi = oi; }
            }
            if (col == 0) { bvalS[tw][b] = mv; bidxS[tw][b] = mi; }
        }
    }
    __syncthreads();
    if (tid < B32) {
        int b = tid;
        float mv = bvalS[0][b]; int mi = bidxS[0][b];
        float v1 = bvalS[1][b]; int i1 = bidxS[1][b];
        if (v1 > mv || (v1 == mv && i1 < mi)) { mv = v1; mi = i1; }
        unsigned u = __float_as_uint(mv);
        u = (u >> 31) ? ~u : (u | 0x80000000u);
        unsigned long long key =
            ((unsigned long long)u << 32) | (unsigned long long)(0xFFFFFFFFu - (unsigned)mi);
        atomicMax(amax + b, key);
    }
}

// ---------------- exact-argmax fix: rescan row, recompute candidates exactly ----------
__global__ __launch_bounds__(256)
void fix_argmax(const float* __restrict__ out, int t, int T,
                const unsigned short* __restrict__ hh, const unsigned short* __restrict__ hl,
                const float* __restrict__ fcw, const float* __restrict__ fcb,
                const unsigned* __restrict__ wn,
                unsigned long long* __restrict__ wbuf, int* __restrict__ tokens)
{
    __shared__ float xs[1024];
    __shared__ float cval[CANDMAX];
    __shared__ int   cand[CANDMAX];
    __shared__ int   lcnt;
    __shared__ float wsum[4];
    __shared__ float sred[4];
    const int b = blockIdx.x, tid = threadIdx.x;
    const int wv = tid >> 6, lane = tid & 63;
    if (tid == 0) lcnt = 0;
    float sq = 0.f;
    for (int k = tid; k < 1024; k += 256) {
        size_t hp = (size_t)(k >> 3) * 256 + (size_t)b * 8 + (k & 7);
        float xv = bf2f(hh[hp]) + bf2f(hl[hp]);
        xs[k] = xv;
        sq += xv * xv;
    }
#pragma unroll
    for (int m = 1; m < 64; m <<= 1) sq += __shfl_xor(sq, m);
    if (lane == 0) sred[wv] = sq;
    __syncthreads();
    float snorm = sred[0] + sred[1] + sred[2] + sred[3];
    unsigned long long key = wbuf[b];
    unsigned hi32 = (unsigned)(key >> 32);
    unsigned fb = (hi32 & 0x80000000u) ? (hi32 & 0x7fffffffu) : ~hi32;
    float m = __uint_as_float(fb);
    float delta = sqrtf(snorm) * __uint_as_float(wn[0]) * (1.01f / 256.0f) + 1e-7f;
    float thr = m - delta;
    const float* orow = out + ((size_t)b * T + t) * VOC;
    for (int i = tid; i < VOC / 4; i += 256) {
        float4 v = ((const float4*)orow)[i];
#pragma unroll
        for (int j = 0; j < 4; ++j) {
            float vv = ((const float*)&v)[j];
            if (vv >= thr) {
                int pos = atomicAdd(&lcnt, 1);
                if (pos < CANDMAX) cand[pos] = i * 4 + j;
            }
        }
    }
    __syncthreads();
    int nc = lcnt < CANDMAX ? lcnt : CANDMAX;
    for (int c = 0; c < nc; ++c) {
        const float* wr = fcw + (size_t)cand[c] * KD;
        float p = 0.f;
        for (int k = tid; k < 1024; k += 256) p += xs[k] * wr[k];
#pragma unroll
        for (int mm = 1; mm < 64; mm <<= 1) p += __shfl_xor(p, mm);
        if (lane == 0) wsum[wv] = p;
        __syncthreads();
        if (tid == 0) cval[c] = wsum[0] + wsum[1] + wsum[2] + wsum[3] + fcb[cand[c]];
        __syncthreads();
    }
    if (tid == 0) {
        float bv = -INFINITY; int bi = 0;
        for (int c = 0; c < nc; ++c) {
            float v = cval[c]; int ii = cand[c];
            if (v > bv || (v == bv && ii < bi) || c == 0) {
                if (c == 0) { bv = v; bi = ii; }
                else if (v > bv || (v == bv && ii < bi)) { bv = v; bi = ii; }
            }
        }
        tokens[b] = bi;
        wbuf[b] = 0ull;
    }
}

// ================= fp32 fallback (round-1, proven) =================
__global__ __launch_bounds__(GEMM_THREADS)
void gemm_k1024(const float* __restrict__ Ax, const float* __restrict__ Ah,
                const float* __restrict__ emb, const int* __restrict__ tokens, int gather0,
                const float* __restrict__ Wx, const float* __restrict__ Wh,
                const float* __restrict__ bias,
                float* __restrict__ C, int N, int KS)
{
    __shared__ float As[BKC * ASTR];
    __shared__ float Ws[2 * BKC * WSTR];
    const int tid = threadIdx.x;
    const int sel = blockIdx.y;
    const int ks  = blockIdx.x % KS;
    const int nt  = blockIdx.x / KS;
    const int n0  = nt * TN;
    const int klen = KD / KS;
    const int k0 = ks * klen;
    const float* A = sel ? Ah : Ax;
    const float* W = sel ? Wh : Wx;
    const bool gather = (sel == 0) && (gather0 != 0);

    const int tb = tid & 7;
    const int tn = tid >> 3;
    const int s_kq = tid & 7;
    const int s_r  = tid >> 3;

    const float* arow0;
    const float* arow1;
    if (gather) {
        arow0 = emb + (size_t)tokens[s_r] * KD;
        arow1 = emb + (size_t)tokens[s_r + 16] * KD;
    } else {
        arow0 = A + (size_t)s_r * KD;
        arow1 = A + (size_t)(s_r + 16) * KD;
    }
    const float* wrow = W + (size_t)(n0 + s_r) * KD;

    float acc[4][8];
#pragma unroll
    for (int i = 0; i < 4; ++i)
#pragma unroll
        for (int j = 0; j < 8; ++j) acc[i][j] = 0.0f;

    for (int kc = 0; kc < klen; kc += BKC) {
        const int kb = k0 + kc + s_kq * 4;
        float4 a0 = *(const float4*)(arow0 + kb);
        float4 a1 = *(const float4*)(arow1 + kb);
        float4 wv[8];
#pragma unroll
        for (int hh = 0; hh < 8; ++hh)
            wv[hh] = *(const float4*)(wrow + (size_t)hh * 16 * KD + kb);

        __syncthreads();
#pragma unroll
        for (int j = 0; j < 4; ++j) {
            As[(s_kq * 4 + j) * ASTR + s_r]      = ((const float*)&a0)[j];
            As[(s_kq * 4 + j) * ASTR + s_r + 16] = ((const float*)&a1)[j];
        }
#pragma unroll
        for (int hh = 0; hh < 8; ++hh) {
            int row = s_r + hh * 16;
            int half = row >> 6;
            int c = row & 63;
            float* wbase = &Ws[half * BKC * WSTR];
#pragma unroll
            for (int j = 0; j < 4; ++j)
                wbase[(s_kq * 4 + j) * WSTR + c] = ((const float*)&wv[hh])[j];
        }
        __syncthreads();

#pragma unroll
        for (int kk = 0; kk < BKC; ++kk) {
            float4 av = *(const float4*)&As[kk * ASTR + 4 * tb];
            float4 w0 = *(const float4*)&Ws[kk * WSTR + 4 * tn];
            float4 w1 = *(const float4*)&Ws[BKC * WSTR + kk * WSTR + 4 * tn];
#pragma unroll
            for (int i = 0; i < 4; ++i) {
                float a = ((const float*)&av)[i];
                acc[i][0] += a * w0.x; acc[i][1] += a * w0.y;
                acc[i][2] += a * w0.z; acc[i][3] += a * w0.w;
                acc[i][4] += a * w1.x; acc[i][5] += a * w1.y;
                acc[i][6] += a * w1.z; acc[i][7] += a * w1.w;
            }
        }
    }

    const int slice = sel * KS + ks;
    float* Cb = C + (size_t)slice * B32 * N;
    float4 bA = make_float4(0.f, 0.f, 0.f, 0.f), bB = bA;
    if (bias != nullptr && ks == 0) {
        bA = *(const float4*)&bias[n0 + 4 * tn];
        bB = *(const float4*)&bias[n0 + 64 + 4 * tn];
    }
#pragma unroll
    for (int i = 0; i < 4; ++i) {
        int b = 4 * tb + i;
        float4 vA = make_float4(acc[i][0] + bA.x, acc[i][1] + bA.y, acc[i][2] + bA.z, acc[i][3] + bA.w);
        float4 vB = make_float4(acc[i][4] + bB.x, acc[i][5] + bB.y, acc[i][6] + bB.z, acc[i][7] + bB.w);
        *(float4*)&Cb[(size_t)b * N + n0 + 4 * tn]       = vA;
        *(float4*)&Cb[(size_t)b * N + n0 + 64 + 4 * tn]  = vB;
    }
}

__global__ __launch_bounds__(256)
void gru_gates(const float* __restrict__ G,
               const float* __restrict__ bih, const float* __restrict__ bhh,
               float* __restrict__ hl)
{
    int idx = blockIdx.x * 256 + threadIdx.x;
    int b = idx >> 10, j = idx & 1023;
    float xr = 0, xz = 0, xn = 0, hr = 0, hz = 0, hn = 0;
#pragma unroll
    for (int ks = 0; ks < KS_GRU; ++ks) {
        const float* gx = G + ((size_t)ks * B32 + b) * 3072;
        const float* gh = G + ((size_t)(KS_GRU + ks) * B32 + b) * 3072;
        xr += gx[j];        xz += gx[1024 + j];  xn += gx[2048 + j];
        hr += gh[j];        hz += gh[1024 + j];  hn += gh[2048 + j];
    }
    float r = sigmoidf_(xr + bih[j] + hr + bhh[j]);
    float z = sigmoidf_(xz + bih[1024 + j] + hz + bhh[1024 + j]);
    float n = tanhf(xn + bih[2048 + j] + r * (hn + bhh[2048 + j]));
    float ho = hl[idx];
    hl[idx] = (1.0f - z) * n + z * ho;
}

__global__ __launch_bounds__(GEMM_THREADS)
void logits_kernel(const float* __restrict__ x,
                   const float* __restrict__ W, const float* __restrict__ bias,
                   float* __restrict__ out, int t, int T,
                   float* __restrict__ pval, int* __restrict__ pidx)
{
    __shared__ float As[BKC * ASTR];
    __shared__ float Ws[2 * BKC * WSTR];
    __shared__ float rval[B32 * 16];
    __shared__ int   ridx[B32 * 16];
    const int tid = threadIdx.x;
    const int n0 = blockIdx.x * TN;
    const int tb = tid & 7;
    const int tn = tid >> 3;
    const int s_kq = tid & 7;
    const int s_r  = tid >> 3;

    const float* arow0 = x + (size_t)s_r * KD;
    const float* arow1 = x + (size_t)(s_r + 16) * KD;
    const float* wrow  = W + (size_t)(n0 + s_r) * KD;

    float acc[4][8];
#pragma unroll
    for (int i = 0; i < 4; ++i)
#pragma unroll
        for (int j = 0; j < 8; ++j) acc[i][j] = 0.0f;

    for (int kc = 0; kc < KD; kc += BKC) {
        const int kb = kc + s_kq * 4;
        float4 a0 = *(const float4*)(arow0 + kb);
        float4 a1 = *(const float4*)(arow1 + kb);
        float4 wv[8];
#pragma unroll
        for (int hh = 0; hh < 8; ++hh)
            wv[hh] = *(const float4*)(wrow + (size_t)hh * 16 * KD + kb);

        __syncthreads();
#pragma unroll
        for (int j = 0; j < 4; ++j) {
            As[(s_kq * 4 + j) * ASTR + s_r]      = ((const float*)&a0)[j];
            As[(s_kq * 4 + j) * ASTR + s_r + 16] = ((const float*)&a1)[j];
        }
#pragma unroll
        for (int hh = 0; hh < 8; ++hh) {
            int row = s_r + hh * 16;
            int half = row >> 6;
            int c = row & 63;
            float* wbase = &Ws[half * BKC * WSTR];
#pragma unroll
            for (int j = 0; j < 4; ++j)
                wbase[(s_kq * 4 + j) * WSTR + c] = ((const float*)&wv[hh])[j];
        }
        __syncthreads();

#pragma unroll
        for (int kk = 0; kk < BKC; ++kk) {
            float4 av = *(const float4*)&As[kk * ASTR + 4 * tb];
            float4 w0 = *(const float4*)&Ws[kk * WSTR + 4 * tn];
            float4 w1 = *(const float4*)&Ws[BKC * WSTR + kk * WSTR + 4 * tn];
#pragma unroll
            for (int i = 0; i < 4; ++i) {
                float a = ((const float*)&av)[i];
                acc[i][0] += a * w0.x; acc[i][1] += a * w0.y;
                acc[i][2] += a * w0.z; acc[i][3] += a * w0.w;
                acc[i][4] += a * w1.x; acc[i][5] += a * w1.y;
                acc[i][6] += a * w1.z; acc[i][7] += a * w1.w;
            }
        }
    }

    float4 bA = *(const float4*)&bias[n0 + 4 * tn];
    float4 bB = *(const float4*)&bias[n0 + 64 + 4 * tn];

    float bestv[4]; int besti[4];
#pragma unroll
    for (int i = 0; i < 4; ++i) { bestv[i] = -INFINITY; besti[i] = INT_MAX; }

#pragma unroll
    for (int i = 0; i < 4; ++i) {
        int b = 4 * tb + i;
        float* orow = out + ((size_t)b * T + t) * VOC;
        float4 vA = make_float4(acc[i][0] + bA.x, acc[i][1] + bA.y, acc[i][2] + bA.z, acc[i][3] + bA.w);
        float4 vB = make_float4(acc[i][4] + bB.x, acc[i][5] + bB.y, acc[i][6] + bB.z, acc[i][7] + bB.w);
        *(float4*)&orow[n0 + 4 * tn]      = vA;
        *(float4*)&orow[n0 + 64 + 4 * tn] = vB;
#pragma unroll
        for (int j = 0; j < 4; ++j) {
            float v = ((const float*)&vA)[j]; int c = n0 + 4 * tn + j;
            if (v > bestv[i] || (v == bestv[i] && c < besti[i])) { bestv[i] = v; besti[i] = c; }
        }
#pragma unroll
        for (int j = 0; j < 4; ++j) {
            float v = ((const float*)&vB)[j]; int c = n0 + 64 + 4 * tn + j;
            if (v > bestv[i] || (v == bestv[i] && c < besti[i])) { bestv[i] = v; besti[i] = c; }
        }
    }
#pragma unroll
    for (int i = 0; i < 4; ++i) {
        rval[(4 * tb + i) * 16 + tn] = bestv[i];
        ridx[(4 * tb + i) * 16 + tn] = besti[i];
    }
    __syncthreads();
    if (tid < B32) {
        int b = tid;
        float bv = -INFINITY; int bi = INT_MAX;
        for (int q = 0; q < 16; ++q) {
            float v = rval[b * 16 + q]; int ii = ridx[b * 16 + q];
            if (v > bv || (v == bv && ii < bi)) { bv = v; bi = ii; }
        }
        pval[(size_t)blockIdx.x * B32 + b] = bv;
        pidx[(size_t)blockIdx.x * B32 + b] = bi;
    }
}

__global__ __launch_bounds__(256)
void amax_final(const float* __restrict__ pval, const int* __restrict__ pidx,
                int nblk, int* __restrict__ tokens)
{
    int tid = threadIdx.x;
    int b = tid >> 3, l8 = tid & 7;
    float bv = -INFINITY; int bi = INT_MAX;
    for (int q = l8; q < nblk; q += 8) {
        float v = pval[(size_t)q * B32 + b]; int ii = pidx[(size_t)q * B32 + b];
        if (v > bv || (v == bv && ii < bi)) { bv = v; bi = ii; }
    }
#pragma unroll
    for (int off = 1; off < 8; off <<= 1) {
        float ov = __shfl_xor(bv, off);
        int   oi = __shfl_xor(bi, off);
        if (ov > bv || (ov == bv && oi < bi)) { bv = ov; bi = oi; }
    }
    if (l8 == 0) tokens[b] = bi;
}

// ---------------- host ----------------
extern "C" void kernel_launch(void* const* d_in, const int* in_sizes, int n_in,
                              void* d_out, int out_size, void* d_ws, size_t ws_size,
                              hipStream_t stream)
{
    const float* z    = (const float*)d_in[0];
    const float* emb  = (const float*)d_in[1];
    const float* wlat = (const float*)d_in[2];
    const float* blat = (const float*)d_in[3];
    const float* wih  = (const float*)d_in[4];
    const float* whh  = (const float*)d_in[5];
    const float* bih  = (const float*)d_in[6];
    const float* bhh  = (const float*)d_in[7];
    const float* fcw  = (const float*)d_in[8];
    const float* fcb  = (const float*)d_in[9];
    float* out = (float*)d_out;
    const int T = out_size / (B32 * VOC);   // 128

    const size_t NEED = 165000000;
    if (ws_size >= NEED) {
        char* p = (char*)d_ws;
        auto take = [&](size_t bytes) { char* r = p; p += (bytes + 255) & ~(size_t)255; return r; };
        unsigned short* fcwPh = (unsigned short*)take((size_t)VOC * KD * 2);
        unsigned short* wihPh = (unsigned short*)take((size_t)NL * 3 * KD * KD * 2);
        unsigned short* wihPl = (unsigned short*)take((size_t)NL * 3 * KD * KD * 2);
        unsigned short* whhPh = (unsigned short*)take((size_t)NL * 3 * KD * KD * 2);
        unsigned short* whhPl = (unsigned short*)take((size_t)NL * 3 * KD * KD * 2);
        unsigned short* hAh   = (unsigned short*)take((size_t)NL * B32 * KD * 2);
        unsigned short* hAl   = (unsigned short*)take((size_t)NL * B32 * KD * 2);
        unsigned short* hBh   = (unsigned short*)take((size_t)NL * B32 * KD * 2);
        unsigned short* hBl   = (unsigned short*)take((size_t)NL * B32 * KD * 2);
        float* G   = (float*)take((size_t)32 * KSF * 6 * 1024 * 4);
        float* h32 = (float*)take((size_t)B32 * NL * KD * 4);
        unsigned long long* wbuf = (unsigned long long*)take(B32 * 8);
        int* tokens = (int*)take(B32 * 4);
        unsigned* wn = (unsigned*)take(256);
        unsigned int* cnt = (unsigned int*)take(32 * 4);

        hipMemsetAsync(cnt, 0, 32 * sizeof(unsigned int), stream);
        hipMemsetAsync(wbuf, 0, B32 * 8, stream);
        hipMemsetAsync(tokens, 0, B32 * 4, stream);
        hipMemsetAsync(wn, 0, 4, stream);

        // one-time packing + column-norm bound
        {
            long nt_fc = VOC / 32;
            long nt_g  = (long)NL * 3 * KD / 32;
            pack_w<<<(unsigned)((nt_fc * 4096 + 255) / 256), 256, 0, stream>>>(fcw, fcwPh, nullptr, nt_fc);
            pack_w<<<(unsigned)((nt_g * 4096 + 255) / 256), 256, 0, stream>>>(wih, wihPh, wihPl, nt_g);
            pack_w<<<(unsigned)((nt_g * 4096 + 255) / 256), 256, 0, stream>>>(whh, whhPh, whhPl, nt_g);
            wnorm_k<<<VOC / 64, 256, 0, stream>>>(fcw, wn);
        }

        // hidden init (fp32), then pack the 3 [32x1024] planes into hA
        gemm_k1024<<<dim3(NL * KD / TN, 1), GEMM_THREADS, 0, stream>>>(
            z, nullptr, nullptr, nullptr, 0, wlat, nullptr, blat, h32, NL * KD, 1);
        pack_w<<<(unsigned)((3L * 4096 + 255) / 256), 256, 0, stream>>>(h32, hAh, hAl, 3);

        const size_t PL = (size_t)B32 * KD;   // one h plane (shorts)
        for (int t = 0; t < T; ++t) {
            unsigned short* ch = (t & 1) ? hBh : hAh;
            unsigned short* cl = (t & 1) ? hBl : hAl;
            unsigned short* nh = (t & 1) ? hAh : hBh;
            unsigned short* nl = (t & 1) ? hAl : hBl;

            if (t > 0) {
                // ch planes hold step t-1's output h (layer 2 at offset 2*PL)
                fix_argmax<<<B32, 256, 0, stream>>>(
                    out, t - 1, T, ch + 2 * PL, cl + 2 * PL, fcw, fcb, wn, wbuf, tokens);
            }
            for (int l = 0; l < NL; ++l) {
                const unsigned short* xh = (l == 0) ? nullptr : nh + (size_t)(l - 1) * PL;
                const unsigned short* xl = (l == 0) ? nullptr : nl + (size_t)(l - 1) * PL;
                gru_fused2<<<32 * KSF, 384, 0, stream>>>(
                    tokens, emb, (l == 0) ? 1 : 0,
                    xh, xl,
                    ch + (size_t)l * PL, cl + (size_t)l * PL,
                    nh + (size_t)l * PL, nl + (size_t)l * PL,
                    wihPh + (size_t)l * 3 * KD * KD, wihPl + (size_t)l * 3 * KD * KD,
                    whhPh + (size_t)l * 3 * KD * KD, whhPl + (size_t)l * 3 * KD * KD,
                    bih + (size_t)l * 3 * KD, bhh + (size_t)l * 3 * KD,
                    G, cnt);
            }
            logits4<<<VOC / 64, 512, 0, stream>>>(
                nh + 2 * PL, nl + 2 * PL, fcwPh, fcb, out, t, T, wbuf);
        }
    } else {
        // fallback: round-1 fp32 path
        float* h      = (float*)d_ws;
        float* G      = h + (size_t)B32 * NL * HID;
        float* pval   = G + (size_t)2 * KS_GRU * B32 * NL * HID;
        int*   pidx   = (int*)(pval + (VOC / TN) * B32);
        int*   tokens = (int*)(pidx + (VOC / TN) * B32);

        hipMemsetAsync(tokens, 0, B32 * sizeof(int), stream);

        gemm_k1024<<<dim3(NL * HID / TN, 1), GEMM_THREADS, 0, stream>>>(
            z, nullptr, nullptr, nullptr, 0, wlat, nullptr, blat, h, NL * HID, 1);

        for (int t = 0; t < T; ++t) {
            for (int l = 0; l < NL; ++l) {
                const float* xA = (l == 0) ? nullptr : (h + (size_t)(l - 1) * B32 * HID);
                dim3 gg((NL * HID / TN) * KS_GRU, 2);
                gemm_k1024<<<gg, GEMM_THREADS, 0, stream>>>(
                    xA, h + (size_t)l * B32 * HID, emb, tokens, (l == 0) ? 1 : 0,
                    wih + (size_t)l * NL * HID * KD, whh + (size_t)l * NL * HID * KD,
                    nullptr, G, NL * HID, KS_GRU);
                gru_gates<<<B32 * HID / 256, 256, 0, stream>>>(
                    G, bih + (size_t)l * NL * HID, bhh + (size_t)l * NL * HID,
                    h + (size_t)l * B32 * HID);
            }
            logits_kernel<<<VOC / TN, GEMM_THREADS, 0, stream>>>(
                h + (size_t)2 * B32 * HID, fcw, fcb, out, t, T, pval, pidx);
            amax_final<<<1, 256, 0, stream>>>(pval, pidx, VOC / TN, tokens);
        }
    }
}

// Round 7
// 13634.322 us; speedup vs baseline: 2.6087x; 2.4590x over previous
//
#include <hip/hip_runtime.h>
#include <math.h>
#include <limits.h>

#define B32 32
#define KD 1024
#define HID 1024
#define VOC 32000
#define NL 3
#define TN 128
#define BKC 32
#define ASTR 36
#define WSTR 68
#define GEMM_THREADS 128
#define KS_GRU 4
#define CANDMAX 64

typedef __attribute__((ext_vector_type(8))) short bf16x8;
typedef __attribute__((ext_vector_type(8))) unsigned short u16x8;
typedef __attribute__((ext_vector_type(16))) float f32x16;

__device__ __forceinline__ float sigmoidf_(float x) { return 1.0f / (1.0f + expf(-x)); }

__device__ __forceinline__ unsigned short f2bf(float f) {
    unsigned u = __float_as_uint(f);
    u = u + 0x7fffu + ((u >> 16) & 1u);
    return (unsigned short)(u >> 16);
}
__device__ __forceinline__ float bf2f(unsigned short h) {
    return __uint_as_float(((unsigned)h) << 16);
}
__device__ __forceinline__ f32x16 MF(bf16x8 a, bf16x8 b, f32x16 c) {
    return __builtin_amdgcn_mfma_f32_32x32x16_bf16(a, b, c, 0, 0, 0);
}

// ---------------- one-time pack: fp32 [ntiles*32][1024] -> fragment-packed hi (+optional lo)
__global__ __launch_bounds__(256)
void pack_w(const float* __restrict__ src, unsigned short* __restrict__ hi,
            unsigned short* __restrict__ lo, long ntiles)
{
    long tid = (long)blockIdx.x * 256 + threadIdx.x;
    long total = ntiles * 4096;
    if (tid >= total) return;
    long tile = tid >> 12;
    int r = (int)(tid & 4095);
    int k8 = r >> 5, c = r & 31;
    const float* s = src + ((size_t)tile * 32 + c) * KD + k8 * 8;
    float4 f0 = ((const float4*)s)[0];
    float4 f1 = ((const float4*)s)[1];
    float ff[8] = {f0.x, f0.y, f0.z, f0.w, f1.x, f1.y, f1.z, f1.w};
    u16x8 h, l;
#pragma unroll
    for (int j = 0; j < 8; ++j) {
        unsigned short hh = f2bf(ff[j]);
        h[j] = hh;
        l[j] = f2bf(ff[j] - bf2f(hh));
    }
    size_t o = ((size_t)tile << 15) + (size_t)k8 * 256 + (size_t)c * 8;
    *(u16x8*)(hi + o) = h;
    if (lo) *(u16x8*)(lo + o) = l;
}

// ---------------- one-time: max column norm of fcw
__global__ __launch_bounds__(256)
void wnorm_k(const float* __restrict__ fcw, unsigned* __restrict__ wn)
{
    const int tid = threadIdx.x;
    const int r = blockIdx.x * 64 + (tid >> 2);
    const int q = tid & 3;
    const float* row = fcw + (size_t)r * KD + q * 256;
    float s = 0.f;
#pragma unroll 8
    for (int i = 0; i < 64; ++i) {
        float4 v = ((const float4*)row)[i];
        s += v.x * v.x + v.y * v.y + v.z * v.z + v.w * v.w;
    }
    s += __shfl_xor(s, 1);
    s += __shfl_xor(s, 2);
    if (q == 0) atomicMax(wn, __float_as_uint(sqrtf(s)));
}

// ---------------- per-step (32 blocks): exact-argmax fix + emb gather + fragment-pack x
// block b: repair argmax for batch row b from step tprev's logits, then gather emb[token]
// and write packed x fragments. do_fix==0 (t==0): token=0, gather only.
__global__ __launch_bounds__(256)
void fix_gather(const float* __restrict__ out, int tprev, int T,
                const unsigned short* __restrict__ hh, const unsigned short* __restrict__ hl,
                const float* __restrict__ fcw, const float* __restrict__ fcb,
                const unsigned* __restrict__ wn,
                unsigned long long* __restrict__ wbuf,
                const float* __restrict__ emb,
                unsigned short* __restrict__ xhi, unsigned short* __restrict__ xlo,
                int do_fix)
{
    __shared__ float xs[1024];
    __shared__ float cval[CANDMAX];
    __shared__ int   cand[CANDMAX];
    __shared__ int   lcnt, stok;
    __shared__ float wsum[4];
    __shared__ float sred[4];
    const int b = blockIdx.x, tid = threadIdx.x;
    const int wv = tid >> 6, lane = tid & 63;

    if (do_fix) {
        if (tid == 0) lcnt = 0;
        float sq = 0.f;
        for (int k = tid; k < 1024; k += 256) {
            size_t hp = (size_t)(k >> 3) * 256 + (size_t)b * 8 + (k & 7);
            float xv = bf2f(hh[hp]) + bf2f(hl[hp]);
            xs[k] = xv;
            sq += xv * xv;
        }
#pragma unroll
        for (int m = 1; m < 64; m <<= 1) sq += __shfl_xor(sq, m);
        if (lane == 0) sred[wv] = sq;
        __syncthreads();
        float snorm = sred[0] + sred[1] + sred[2] + sred[3];
        unsigned long long key = wbuf[b];
        unsigned hi32 = (unsigned)(key >> 32);
        unsigned fb = (hi32 & 0x80000000u) ? (hi32 & 0x7fffffffu) : ~hi32;
        float m = __uint_as_float(fb);
        float delta = sqrtf(snorm) * __uint_as_float(wn[0]) * (1.01f / 256.0f) + 1e-7f;
        float thr = m - delta;
        const float* orow = out + ((size_t)b * T + tprev) * VOC;
        for (int i = tid; i < VOC / 4; i += 256) {
            float4 v = ((const float4*)orow)[i];
#pragma unroll
            for (int j = 0; j < 4; ++j) {
                float vv = ((const float*)&v)[j];
                if (vv >= thr) {
                    int pos = atomicAdd(&lcnt, 1);
                    if (pos < CANDMAX) cand[pos] = i * 4 + j;
                }
            }
        }
        __syncthreads();
        int nc = lcnt < CANDMAX ? lcnt : CANDMAX;
        for (int c = 0; c < nc; ++c) {
            const float* wr = fcw + (size_t)cand[c] * KD;
            float p = 0.f;
            for (int k = tid; k < 1024; k += 256) p += xs[k] * wr[k];
#pragma unroll
            for (int mm = 1; mm < 64; mm <<= 1) p += __shfl_xor(p, mm);
            if (lane == 0) wsum[wv] = p;
            __syncthreads();
            if (tid == 0) cval[c] = wsum[0] + wsum[1] + wsum[2] + wsum[3] + fcb[cand[c]];
            __syncthreads();
        }
        if (tid == 0) {
            float bv = -INFINITY; int bi = 0;
            for (int c = 0; c < nc; ++c) {
                float v = cval[c]; int ii = cand[c];
                if (c == 0 || v > bv || (v == bv && ii < bi)) { bv = v; bi = ii; }
            }
            stok = bi;
            wbuf[b] = 0ull;   // reset for this step's logits atomics
        }
    }
    __syncthreads();
    int tok = do_fix ? stok : 0;
    if (tid < 128) {
        const float* er = emb + (size_t)tok * KD + (size_t)tid * 8;
        float4 f0 = ((const float4*)er)[0];
        float4 f1 = ((const float4*)er)[1];
        float ff[8] = {f0.x, f0.y, f0.z, f0.w, f1.x, f1.y, f1.z, f1.w};
        u16x8 h, l;
#pragma unroll
        for (int j = 0; j < 8; ++j) {
            unsigned short hv = f2bf(ff[j]);
            h[j] = hv;
            l[j] = f2bf(ff[j] - bf2f(hv));
        }
        size_t o = (size_t)tid * 256 + (size_t)b * 8;
        *(u16x8*)(xhi + o) = h;
        *(u16x8*)(xlo + o) = l;
    }
}

// ---------------- GRU GEMM (R3 verbatim): 128 blocks x 384 thr; block=(jt,ks4), wave=panel
__global__ __launch_bounds__(384)
void gru_gemm(const unsigned short* __restrict__ xhi, const unsigned short* __restrict__ xlo,
              const unsigned short* __restrict__ hhi, const unsigned short* __restrict__ hlo,
              const unsigned short* __restrict__ wihhi, const unsigned short* __restrict__ wihlo,
              const unsigned short* __restrict__ whhhi, const unsigned short* __restrict__ whhlo,
              float* __restrict__ G)
{
    const int bid = blockIdx.x;
    const int jt = bid >> 2, ks4 = bid & 3;
    const int w = threadIdx.x >> 6, lane = threadIdx.x & 63;
    const int gate = (w < 3) ? w : w - 3;
    const unsigned short* Ah = (w < 3) ? xhi : hhi;
    const unsigned short* Al = (w < 3) ? xlo : hlo;
    const size_t woff = ((size_t)(gate * 32 + jt)) << 15;
    const unsigned short* Wh = ((w < 3) ? wihhi : whhhi) + woff;
    const unsigned short* Wl = ((w < 3) ? wihlo : whhlo) + woff;

    const size_t lo8 = (size_t)lane * 8;
    const int kbase = ks4 * 16;

    f32x16 acc = {0,0,0,0,0,0,0,0,0,0,0,0,0,0,0,0};
    size_t o0 = (size_t)kbase * 512 + lo8;
    bf16x8 ah0 = *(const bf16x8*)(Ah + o0), al0 = *(const bf16x8*)(Al + o0);
    bf16x8 wh0 = *(const bf16x8*)(Wh + o0), wl0 = *(const bf16x8*)(Wl + o0);
#pragma unroll 4
    for (int i = 0; i < 16; ++i) {
        size_t on = (size_t)(kbase + ((i + 1) & 15)) * 512 + lo8;
        bf16x8 ahn = *(const bf16x8*)(Ah + on), aln = *(const bf16x8*)(Al + on);
        bf16x8 whn = *(const bf16x8*)(Wh + on), wln = *(const bf16x8*)(Wl + on);
        acc = MF(ah0, wh0, acc);
        acc = MF(al0, wh0, acc);
        acc = MF(ah0, wl0, acc);
        ah0 = ahn; al0 = aln; wh0 = whn; wl0 = wln;
    }

    const int kg = lane >> 5, c = lane & 31;
    float* Gb = G + (((size_t)(jt * 4 + ks4) * 6 + w) * B32) * 32;
#pragma unroll
    for (int r = 0; r < 16; ++r) {
        int b = (r & 3) + 8 * (r >> 2) + 4 * kg;
        Gb[b * 32 + c] = acc[r];
    }
}

// ---------------- gates (R3 verbatim): sum partials, activations, in-place packed h update
__global__ __launch_bounds__(256)
void gru_gates2(const float* __restrict__ G,
                const float* __restrict__ bih, const float* __restrict__ bhh,
                unsigned short* __restrict__ hhi, unsigned short* __restrict__ hlo)
{
    int idx = blockIdx.x * 256 + threadIdx.x;   // 32768
    int b = idx >> 10, j = idx & 1023;
    int jt = j >> 5, c = j & 31;
    float s0 = 0, s1 = 0, s2 = 0, s3 = 0, s4 = 0, s5 = 0;
#pragma unroll
    for (int ks = 0; ks < 4; ++ks) {
        const float* base = G + (((size_t)(jt * 4 + ks) * 6) * B32 + b) * 32 + c;
        s0 += base[0];
        s1 += base[1024];
        s2 += base[2048];
        s3 += base[3072];
        s4 += base[4096];
        s5 += base[5120];
    }
    float rg = sigmoidf_(s0 + bih[j] + s3 + bhh[j]);
    float zg = sigmoidf_(s1 + bih[KD + j] + s4 + bhh[KD + j]);
    float ng = tanhf(s2 + bih[2 * KD + j] + rg * (s5 + bhh[2 * KD + j]));
    size_t hp = (size_t)(j >> 3) * 256 + (size_t)b * 8 + (j & 7);
    float hold = bf2f(hhi[hp]) + bf2f(hlo[hp]);
    float hnew = (1.0f - zg) * ng + zg * hold;
    unsigned short hh = f2bf(hnew);
    hhi[hp] = hh;
    hlo[hp] = f2bf(hnew - bf2f(hh));
}

// ---------------- logits: hi-only W, R3 shape (250 blocks x 256 thr, wave = one 32-col tile)
__global__ __launch_bounds__(256)
void logits5(const unsigned short* __restrict__ xh, const unsigned short* __restrict__ xl,
             const unsigned short* __restrict__ wh,
             const float* __restrict__ bias, float* __restrict__ out, int t, int T,
             unsigned long long* __restrict__ wbuf)
{
    __shared__ float bvalS[4][B32];
    __shared__ int   bidxS[4][B32];
    const int tid = threadIdx.x;
    const int w = tid >> 6, lane = tid & 63;
    const int tile = blockIdx.x * 4 + w;
    const int n0 = tile * 32;
    const unsigned short* Wt = wh + ((size_t)tile << 15);
    const size_t lo8 = (size_t)lane * 8;

    f32x16 acc = {0,0,0,0,0,0,0,0,0,0,0,0,0,0,0,0};
    bf16x8 ah0 = *(const bf16x8*)(xh + lo8),       al0 = *(const bf16x8*)(xl + lo8);
    bf16x8 wv0 = *(const bf16x8*)(Wt + lo8);
    bf16x8 ah1 = *(const bf16x8*)(xh + 512 + lo8), al1 = *(const bf16x8*)(xl + 512 + lo8);
    bf16x8 wv1 = *(const bf16x8*)(Wt + 512 + lo8);

    for (int i = 0; i < 64; ++i) {
        size_t on = (size_t)((i + 2) & 63) * 512 + lo8;
        bf16x8 ahn = *(const bf16x8*)(xh + on), aln = *(const bf16x8*)(xl + on);
        bf16x8 wvn = *(const bf16x8*)(Wt + on);
        acc = MF(ah0, wv0, acc);
        acc = MF(al0, wv0, acc);
        ah0 = ah1; al0 = al1; wv0 = wv1;
        ah1 = ahn; al1 = aln; wv1 = wvn;
    }

    const int kg = lane >> 5, col = lane & 31;
    const float bb = bias[n0 + col];
#pragma unroll
    for (int r = 0; r < 16; ++r) {
        int b = (r & 3) + 8 * (r >> 2) + 4 * kg;
        float v = acc[r] + bb;
        out[((size_t)b * T + t) * VOC + n0 + col] = v;
        float mv = v; int mi = n0 + col;
#pragma unroll
        for (int m = 1; m < 32; m <<= 1) {
            float ov = __shfl_xor(mv, m);
            int   oi = __shfl_xor(mi, m);
            if (ov > mv || (ov == mv && oi < mi)) { mv = ov; mi = oi; }
        }
        if (col == 0) { bvalS[w][b] = mv; bidxS[w][b] = mi; }   // kg halves write disjoint b
    }
    __syncthreads();
    if (tid < B32) {
        int b = tid;
        float mv = bvalS[0][b]; int mi = bidxS[0][b];
#pragma unroll
        for (int q = 1; q < 4; ++q) {
            float v = bvalS[q][b]; int ii = bidxS[q][b];
            if (v > mv || (v == mv && ii < mi)) { mv = v; mi = ii; }
        }
        unsigned u = __float_as_uint(mv);
        u = (u >> 31) ? ~u : (u | 0x80000000u);
        unsigned long long key =
            ((unsigned long long)u << 32) | (unsigned long long)(0xFFFFFFFFu - (unsigned)mi);
        atomicMax(wbuf + b, key);
    }
}

// ================= fp32 fallback (round-1, proven) =================
__global__ __launch_bounds__(GEMM_THREADS)
void gemm_k1024(const float* __restrict__ Ax, const float* __restrict__ Ah,
                const float* __restrict__ emb, const int* __restrict__ tokens, int gather0,
                const float* __restrict__ Wx, const float* __restrict__ Wh,
                const float* __restrict__ bias,
                float* __restrict__ C, int N, int KS)
{
    __shared__ float As[BKC * ASTR];
    __shared__ float Ws[2 * BKC * WSTR];
    const int tid = threadIdx.x;
    const int sel = blockIdx.y;
    const int ks  = blockIdx.x % KS;
    const int nt  = blockIdx.x / KS;
    const int n0  = nt * TN;
    const int klen = KD / KS;
    const int k0 = ks * klen;
    const float* A = sel ? Ah : Ax;
    const float* W = sel ? Wh : Wx;
    const bool gather = (sel == 0) && (gather0 != 0);

    const int tb = tid & 7;
    const int tn = tid >> 3;
    const int s_kq = tid & 7;
    const int s_r  = tid >> 3;

    const float* arow0;
    const float* arow1;
    if (gather) {
        arow0 = emb + (size_t)tokens[s_r] * KD;
        arow1 = emb + (size_t)tokens[s_r + 16] * KD;
    } else {
        arow0 = A + (size_t)s_r * KD;
        arow1 = A + (size_t)(s_r + 16) * KD;
    }
    const float* wrow = W + (size_t)(n0 + s_r) * KD;

    float acc[4][8];
#pragma unroll
    for (int i = 0; i < 4; ++i)
#pragma unroll
        for (int j = 0; j < 8; ++j) acc[i][j] = 0.0f;

    for (int kc = 0; kc < klen; kc += BKC) {
        const int kb = k0 + kc + s_kq * 4;
        float4 a0 = *(const float4*)(arow0 + kb);
        float4 a1 = *(const float4*)(arow1 + kb);
        float4 wv[8];
#pragma unroll
        for (int hh = 0; hh < 8; ++hh)
            wv[hh] = *(const float4*)(wrow + (size_t)hh * 16 * KD + kb);

        __syncthreads();
#pragma unroll
        for (int j = 0; j < 4; ++j) {
            As[(s_kq * 4 + j) * ASTR + s_r]      = ((const float*)&a0)[j];
            As[(s_kq * 4 + j) * ASTR + s_r + 16] = ((const float*)&a1)[j];
        }
#pragma unroll
        for (int hh = 0; hh < 8; ++hh) {
            int row = s_r + hh * 16;
            int half = row >> 6;
            int c = row & 63;
            float* wbase = &Ws[half * BKC * WSTR];
#pragma unroll
            for (int j = 0; j < 4; ++j)
                wbase[(s_kq * 4 + j) * WSTR + c] = ((const float*)&wv[hh])[j];
        }
        __syncthreads();

#pragma unroll
        for (int kk = 0; kk < BKC; ++kk) {
            float4 av = *(const float4*)&As[kk * ASTR + 4 * tb];
            float4 w0 = *(const float4*)&Ws[kk * WSTR + 4 * tn];
            float4 w1 = *(const float4*)&Ws[BKC * WSTR + kk * WSTR + 4 * tn];
#pragma unroll
            for (int i = 0; i < 4; ++i) {
                float a = ((const float*)&av)[i];
                acc[i][0] += a * w0.x; acc[i][1] += a * w0.y;
                acc[i][2] += a * w0.z; acc[i][3] += a * w0.w;
                acc[i][4] += a * w1.x; acc[i][5] += a * w1.y;
                acc[i][6] += a * w1.z; acc[i][7] += a * w1.w;
            }
        }
    }

    const int slice = sel * KS + ks;
    float* Cb = C + (size_t)slice * B32 * N;
    float4 bA = make_float4(0.f, 0.f, 0.f, 0.f), bB = bA;
    if (bias != nullptr && ks == 0) {
        bA = *(const float4*)&bias[n0 + 4 * tn];
        bB = *(const float4*)&bias[n0 + 64 + 4 * tn];
    }
#pragma unroll
    for (int i = 0; i < 4; ++i) {
        int b = 4 * tb + i;
        float4 vA = make_float4(acc[i][0] + bA.x, acc[i][1] + bA.y, acc[i][2] + bA.z, acc[i][3] + bA.w);
        float4 vB = make_float4(acc[i][4] + bB.x, acc[i][5] + bB.y, acc[i][6] + bB.z, acc[i][7] + bB.w);
        *(float4*)&Cb[(size_t)b * N + n0 + 4 * tn]       = vA;
        *(float4*)&Cb[(size_t)b * N + n0 + 64 + 4 * tn]  = vB;
    }
}

__global__ __launch_bounds__(256)
void gru_gates(const float* __restrict__ G,
               const float* __restrict__ bih, const float* __restrict__ bhh,
               float* __restrict__ hl)
{
    int idx = blockIdx.x * 256 + threadIdx.x;
    int b = idx >> 10, j = idx & 1023;
    float xr = 0, xz = 0, xn = 0, hr = 0, hz = 0, hn = 0;
#pragma unroll
    for (int ks = 0; ks < KS_GRU; ++ks) {
        const float* gx = G + ((size_t)ks * B32 + b) * 3072;
        const float* gh = G + ((size_t)(KS_GRU + ks) * B32 + b) * 3072;
        xr += gx[j];        xz += gx[1024 + j];  xn += gx[2048 + j];
        hr += gh[j];        hz += gh[1024 + j];  hn += gh[2048 + j];
    }
    float r = sigmoidf_(xr + bih[j] + hr + bhh[j]);
    float z = sigmoidf_(xz + bih[1024 + j] + hz + bhh[1024 + j]);
    float n = tanhf(xn + bih[2048 + j] + r * (hn + bhh[2048 + j]));
    float ho = hl[idx];
    hl[idx] = (1.0f - z) * n + z * ho;
}

__global__ __launch_bounds__(GEMM_THREADS)
void logits_kernel(const float* __restrict__ x,
                   const float* __restrict__ W, const float* __restrict__ bias,
                   float* __restrict__ out, int t, int T,
                   float* __restrict__ pval, int* __restrict__ pidx)
{
    __shared__ float As[BKC * ASTR];
    __shared__ float Ws[2 * BKC * WSTR];
    __shared__ float rval[B32 * 16];
    __shared__ int   ridx[B32 * 16];
    const int tid = threadIdx.x;
    const int n0 = blockIdx.x * TN;
    const int tb = tid & 7;
    const int tn = tid >> 3;
    const int s_kq = tid & 7;
    const int s_r  = tid >> 3;

    const float* arow0 = x + (size_t)s_r * KD;
    const float* arow1 = x + (size_t)(s_r + 16) * KD;
    const float* wrow  = W + (size_t)(n0 + s_r) * KD;

    float acc[4][8];
#pragma unroll
    for (int i = 0; i < 4; ++i)
#pragma unroll
        for (int j = 0; j < 8; ++j) acc[i][j] = 0.0f;

    for (int kc = 0; kc < KD; kc += BKC) {
        const int kb = kc + s_kq * 4;
        float4 a0 = *(const float4*)(arow0 + kb);
        float4 a1 = *(const float4*)(arow1 + kb);
        float4 wv[8];
#pragma unroll
        for (int hh = 0; hh < 8; ++hh)
            wv[hh] = *(const float4*)(wrow + (size_t)hh * 16 * KD + kb);

        __syncthreads();
#pragma unroll
        for (int j = 0; j < 4; ++j) {
            As[(s_kq * 4 + j) * ASTR + s_r]      = ((const float*)&a0)[j];
            As[(s_kq * 4 + j) * ASTR + s_r + 16] = ((const float*)&a1)[j];
        }
#pragma unroll
        for (int hh = 0; hh < 8; ++hh) {
            int row = s_r + hh * 16;
            int half = row >> 6;
            int c = row & 63;
            float* wbase = &Ws[half * BKC * WSTR];
#pragma unroll
            for (int j = 0; j < 4; ++j)
                wbase[(s_kq * 4 + j) * WSTR + c] = ((const float*)&wv[hh])[j];
        }
        __syncthreads();

#pragma unroll
        for (int kk = 0; kk < BKC; ++kk) {
            float4 av = *(const float4*)&As[kk * ASTR + 4 * tb];
            float4 w0 = *(const float4*)&Ws[kk * WSTR + 4 * tn];
            float4 w1 = *(const float4*)&Ws[BKC * WSTR + kk * WSTR + 4 * tn];
#pragma unroll
            for (int i = 0; i < 4; ++i) {
                float a = ((const float*)&av)[i];
                acc[i][0] += a * w0.x; acc[i][1] += a * w0.y;
                acc[i][2] += a * w0.z; acc[i][3] += a * w0.w;
                acc[i][4] += a * w1.x; acc[i][5] += a * w1.y;
                acc[i][6] += a * w1.z; acc[i][7] += a * w1.w;
            }
        }
    }

    float4 bA = *(const float4*)&bias[n0 + 4 * tn];
    float4 bB = *(const float4*)&bias[n0 + 64 + 4 * tn];

    float bestv[4]; int besti[4];
#pragma unroll
    for (int i = 0; i < 4; ++i) { bestv[i] = -INFINITY; besti[i] = INT_MAX; }

#pragma unroll
    for (int i = 0; i < 4; ++i) {
        int b = 4 * tb + i;
        float* orow = out + ((size_t)b * T + t) * VOC;
        float4 vA = make_float4(acc[i][0] + bA.x, acc[i][1] + bA.y, acc[i][2] + bA.z, acc[i][3] + bA.w);
        float4 vB = make_float4(acc[i][4] + bB.x, acc[i][5] + bB.y, acc[i][6] + bB.z, acc[i][7] + bB.w);
        *(float4*)&orow[n0 + 4 * tn]      = vA;
        *(float4*)&orow[n0 + 64 + 4 * tn] = vB;
#pragma unroll
        for (int j = 0; j < 4; ++j) {
            float v = ((const float*)&vA)[j]; int c = n0 + 4 * tn + j;
            if (v > bestv[i] || (v == bestv[i] && c < besti[i])) { bestv[i] = v; besti[i] = c; }
        }
#pragma unroll
        for (int j = 0; j < 4; ++j) {
            float v = ((const float*)&vB)[j]; int c = n0 + 64 + 4 * tn + j;
            if (v > bestv[i] || (v == bestv[i] && c < besti[i])) { bestv[i] = v; besti[i] = c; }
        }
    }
#pragma unroll
    for (int i = 0; i < 4; ++i) {
        rval[(4 * tb + i) * 16 + tn] = bestv[i];
        ridx[(4 * tb + i) * 16 + tn] = besti[i];
    }
    __syncthreads();
    if (tid < B32) {
        int b = tid;
        float bv = -INFINITY; int bi = INT_MAX;
        for (int q = 0; q < 16; ++q) {
            float v = rval[b * 16 + q]; int ii = ridx[b * 16 + q];
            if (v > bv || (v == bv && ii < bi)) { bv = v; bi = ii; }
        }
        pval[(size_t)blockIdx.x * B32 + b] = bv;
        pidx[(size_t)blockIdx.x * B32 + b] = bi;
    }
}

__global__ __launch_bounds__(256)
void amax_final(const float* __restrict__ pval, const int* __restrict__ pidx,
                int nblk, int* __restrict__ tokens)
{
    int tid = threadIdx.x;
    int b = tid >> 3, l8 = tid & 7;
    float bv = -INFINITY; int bi = INT_MAX;
    for (int q = l8; q < nblk; q += 8) {
        float v = pval[(size_t)q * B32 + b]; int ii = pidx[(size_t)q * B32 + b];
        if (v > bv || (v == bv && ii < bi)) { bv = v; bi = ii; }
    }
#pragma unroll
    for (int off = 1; off < 8; off <<= 1) {
        float ov = __shfl_xor(bv, off);
        int   oi = __shfl_xor(bi, off);
        if (ov > bv || (ov == bv && oi < bi)) { bv = ov; bi = oi; }
    }
    if (l8 == 0) tokens[b] = bi;
}

// ---------------- host ----------------
extern "C" void kernel_launch(void* const* d_in, const int* in_sizes, int n_in,
                              void* d_out, int out_size, void* d_ws, size_t ws_size,
                              hipStream_t stream)
{
    const float* z    = (const float*)d_in[0];
    const float* emb  = (const float*)d_in[1];
    const float* wlat = (const float*)d_in[2];
    const float* blat = (const float*)d_in[3];
    const float* wih  = (const float*)d_in[4];
    const float* whh  = (const float*)d_in[5];
    const float* bih  = (const float*)d_in[6];
    const float* bhh  = (const float*)d_in[7];
    const float* fcw  = (const float*)d_in[8];
    const float* fcb  = (const float*)d_in[9];
    float* out = (float*)d_out;
    const int T = out_size / (B32 * VOC);   // 128

    const size_t NEED = 152000000;
    if (ws_size >= NEED) {
        char* p = (char*)d_ws;
        auto take = [&](size_t bytes) { char* r = p; p += (bytes + 255) & ~(size_t)255; return r; };
        unsigned short* fcwPh = (unsigned short*)take((size_t)VOC * KD * 2);
        unsigned short* wihPh = (unsigned short*)take((size_t)NL * 3 * KD * KD * 2);
        unsigned short* wihPl = (unsigned short*)take((size_t)NL * 3 * KD * KD * 2);
        unsigned short* whhPh = (unsigned short*)take((size_t)NL * 3 * KD * KD * 2);
        unsigned short* whhPl = (unsigned short*)take((size_t)NL * 3 * KD * KD * 2);
        unsigned short* hPh   = (unsigned short*)take((size_t)NL * B32 * KD * 2);
        unsigned short* hPl   = (unsigned short*)take((size_t)NL * B32 * KD * 2);
        unsigned short* xPh   = (unsigned short*)take((size_t)B32 * KD * 2);
        unsigned short* xPl   = (unsigned short*)take((size_t)B32 * KD * 2);
        float* G   = (float*)take((size_t)32 * 4 * 6 * B32 * 32 * 4);
        float* h32 = (float*)take((size_t)B32 * NL * KD * 4);
        unsigned long long* wbuf = (unsigned long long*)take(B32 * 8);
        unsigned* wn = (unsigned*)take(256);

        hipMemsetAsync(wbuf, 0, B32 * 8, stream);
        hipMemsetAsync(wn, 0, 4, stream);

        // one-time packing (fcw hi-only; GRU weights hi+lo) + column-norm bound
        {
            long nt_fc = VOC / 32;
            long nt_g  = (long)NL * 3 * KD / 32;
            pack_w<<<(unsigned)((nt_fc * 4096 + 255) / 256), 256, 0, stream>>>(fcw, fcwPh, nullptr, nt_fc);
            pack_w<<<(unsigned)((nt_g * 4096 + 255) / 256), 256, 0, stream>>>(wih, wihPh, wihPl, nt_g);
            pack_w<<<(unsigned)((nt_g * 4096 + 255) / 256), 256, 0, stream>>>(whh, whhPh, whhPl, nt_g);
            wnorm_k<<<VOC / 64, 256, 0, stream>>>(fcw, wn);
        }

        // hidden init (fp32), then pack the 3 [32x1024] planes
        gemm_k1024<<<dim3(NL * KD / TN, 1), GEMM_THREADS, 0, stream>>>(
            z, nullptr, nullptr, nullptr, 0, wlat, nullptr, blat, h32, NL * KD, 1);
        pack_w<<<(unsigned)((3L * 4096 + 255) / 256), 256, 0, stream>>>(h32, hPh, hPl, 3);

        const size_t PL = (size_t)B32 * KD;
        for (int t = 0; t < T; ++t) {
            // exact argmax of step t-1 (from approx logits + candidate recompute) + emb gather/pack
            fix_gather<<<B32, 256, 0, stream>>>(
                out, t - 1, T, hPh + 2 * PL, hPl + 2 * PL, fcw, fcb, wn, wbuf,
                emb, xPh, xPl, t > 0 ? 1 : 0);

            for (int l = 0; l < NL; ++l) {
                const unsigned short* xh = (l == 0) ? xPh : hPh + (size_t)(l - 1) * PL;
                const unsigned short* xl = (l == 0) ? xPl : hPl + (size_t)(l - 1) * PL;
                gru_gemm<<<128, 384, 0, stream>>>(
                    xh, xl,
                    hPh + (size_t)l * PL, hPl + (size_t)l * PL,
                    wihPh + (size_t)l * 3 * KD * KD, wihPl + (size_t)l * 3 * KD * KD,
                    whhPh + (size_t)l * 3 * KD * KD, whhPl + (size_t)l * 3 * KD * KD,
                    G);
                gru_gates2<<<128, 256, 0, stream>>>(
                    G, bih + (size_t)l * 3 * KD, bhh + (size_t)l * 3 * KD,
                    hPh + (size_t)l * PL, hPl + (size_t)l * PL);
            }
            logits5<<<250, 256, 0, stream>>>(
                hPh + 2 * PL, hPl + 2 * PL, fcwPh, fcb, out, t, T, wbuf);
        }
    } else {
        // fallback: round-1 fp32 path
        float* h      = (float*)d_ws;
        float* G      = h + (size_t)B32 * NL * HID;
        float* pval   = G + (size_t)2 * KS_GRU * B32 * NL * HID;
        int*   pidx   = (int*)(pval + (VOC / TN) * B32);
        int*   tokens = (int*)(pidx + (VOC / TN) * B32);

        hipMemsetAsync(tokens, 0, B32 * sizeof(int), stream);

        gemm_k1024<<<dim3(NL * HID / TN, 1), GEMM_THREADS, 0, stream>>>(
            z, nullptr, nullptr, nullptr, 0, wlat, nullptr, blat, h, NL * HID, 1);

        for (int t = 0; t < T; ++t) {
            for (int l = 0; l < NL; ++l) {
                const float* xA = (l == 0) ? nullptr : (h + (size_t)(l - 1) * B32 * HID);
                dim3 gg((NL * HID / TN) * KS_GRU, 2);
                gemm_k1024<<<gg, GEMM_THREADS, 0, stream>>>(
                    xA, h + (size_t)l * B32 * HID, emb, tokens, (l == 0) ? 1 : 0,
                    wih + (size_t)l * NL * HID * KD, whh + (size_t)l * NL * HID * KD,
                    nullptr, G, NL * HID, KS_GRU);
                gru_gates<<<B32 * HID / 256, 256, 0, stream>>>(
                    G, bih + (size_t)l * NL * HID, bhh + (size_t)l * NL * HID,
                    h + (size_t)l * B32 * HID);
            }
            logits_kernel<<<VOC / TN, GEMM_THREADS, 0, stream>>>(
                h + (size_t)2 * B32 * HID, fcw, fcb, out, t, T, pval, pidx);
            amax_final<<<1, 256, 0, stream>>>(pval, pidx, VOC / TN, tokens);
        }
    }
}

// Round 8
// 10883.964 us; speedup vs baseline: 3.2680x; 1.2527x over previous
//
#include <hip/hip_runtime.h>
#include <math.h>
#include <limits.h>

#define B32 32
#define KD 1024
#define HID 1024
#define VOC 32000
#define NL 3
#define TN 128
#define BKC 32
#define ASTR 36
#define WSTR 68
#define GEMM_THREADS 128
#define KS_GRU 4
#define CANDMAX 64

typedef __attribute__((ext_vector_type(8))) short bf16x8;
typedef __attribute__((ext_vector_type(8))) unsigned short u16x8;
typedef __attribute__((ext_vector_type(16))) float f32x16;

__device__ __forceinline__ float sigmoidf_(float x) { return 1.0f / (1.0f + expf(-x)); }

__device__ __forceinline__ unsigned short f2bf(float f) {
    unsigned u = __float_as_uint(f);
    u = u + 0x7fffu + ((u >> 16) & 1u);
    return (unsigned short)(u >> 16);
}
__device__ __forceinline__ float bf2f(unsigned short h) {
    return __uint_as_float(((unsigned)h) << 16);
}
__device__ __forceinline__ f32x16 MF(bf16x8 a, bf16x8 b, f32x16 c) {
    return __builtin_amdgcn_mfma_f32_32x32x16_bf16(a, b, c, 0, 0, 0);
}

// ---------------- one-time pack: fp32 [ntiles*32][1024] -> fragment-packed hi (+optional lo)
__global__ __launch_bounds__(256)
void pack_w(const float* __restrict__ src, unsigned short* __restrict__ hi,
            unsigned short* __restrict__ lo, long ntiles)
{
    long tid = (long)blockIdx.x * 256 + threadIdx.x;
    long total = ntiles * 4096;
    if (tid >= total) return;
    long tile = tid >> 12;
    int r = (int)(tid & 4095);
    int k8 = r >> 5, c = r & 31;
    const float* s = src + ((size_t)tile * 32 + c) * KD + k8 * 8;
    float4 f0 = ((const float4*)s)[0];
    float4 f1 = ((const float4*)s)[1];
    float ff[8] = {f0.x, f0.y, f0.z, f0.w, f1.x, f1.y, f1.z, f1.w};
    u16x8 h, l;
#pragma unroll
    for (int j = 0; j < 8; ++j) {
        unsigned short hh = f2bf(ff[j]);
        h[j] = hh;
        l[j] = f2bf(ff[j] - bf2f(hh));
    }
    size_t o = ((size_t)tile << 15) + (size_t)k8 * 256 + (size_t)c * 8;
    *(u16x8*)(hi + o) = h;
    if (lo) *(u16x8*)(lo + o) = l;
}

// ---------------- one-time: max column norm of fcw
__global__ __launch_bounds__(256)
void wnorm_k(const float* __restrict__ fcw, unsigned* __restrict__ wn)
{
    const int tid = threadIdx.x;
    const int r = blockIdx.x * 64 + (tid >> 2);
    const int q = tid & 3;
    const float* row = fcw + (size_t)r * KD + q * 256;
    float s = 0.f;
#pragma unroll 8
    for (int i = 0; i < 64; ++i) {
        float4 v = ((const float4*)row)[i];
        s += v.x * v.x + v.y * v.y + v.z * v.z + v.w * v.w;
    }
    s += __shfl_xor(s, 1);
    s += __shfl_xor(s, 2);
    if (q == 0) atomicMax(wn, __float_as_uint(sqrtf(s)));
}

// ---------------- per-step (32 blocks): exact-argmax fix + emb gather + fragment-pack x
__global__ __launch_bounds__(256)
void fix_gather(const float* __restrict__ out, int tprev, int T,
                const unsigned short* __restrict__ hh, const unsigned short* __restrict__ hl,
                const float* __restrict__ fcw, const float* __restrict__ fcb,
                const unsigned* __restrict__ wn,
                unsigned long long* __restrict__ wbuf,
                const float* __restrict__ emb,
                unsigned short* __restrict__ xhi, unsigned short* __restrict__ xlo,
                int do_fix)
{
    __shared__ float xs[1024];
    __shared__ float cval[CANDMAX];
    __shared__ int   cand[CANDMAX];
    __shared__ int   lcnt, stok;
    __shared__ float wsum[4];
    __shared__ float sred[4];
    const int b = blockIdx.x, tid = threadIdx.x;
    const int wv = tid >> 6, lane = tid & 63;

    if (do_fix) {
        if (tid == 0) lcnt = 0;
        float sq = 0.f;
        for (int k = tid; k < 1024; k += 256) {
            size_t hp = (size_t)(k >> 3) * 256 + (size_t)b * 8 + (k & 7);
            float xv = bf2f(hh[hp]) + bf2f(hl[hp]);
            xs[k] = xv;
            sq += xv * xv;
        }
#pragma unroll
        for (int m = 1; m < 64; m <<= 1) sq += __shfl_xor(sq, m);
        if (lane == 0) sred[wv] = sq;
        __syncthreads();
        float snorm = sred[0] + sred[1] + sred[2] + sred[3];
        unsigned long long key = wbuf[b];
        unsigned hi32 = (unsigned)(key >> 32);
        unsigned fb = (hi32 & 0x80000000u) ? (hi32 & 0x7fffffffu) : ~hi32;
        float m = __uint_as_float(fb);
        float delta = sqrtf(snorm) * __uint_as_float(wn[0]) * (1.01f / 256.0f) + 1e-7f;
        float thr = m - delta;
        const float* orow = out + ((size_t)b * T + tprev) * VOC;
        for (int i = tid; i < VOC / 4; i += 256) {
            float4 v = ((const float4*)orow)[i];
#pragma unroll
            for (int j = 0; j < 4; ++j) {
                float vv = ((const float*)&v)[j];
                if (vv >= thr) {
                    int pos = atomicAdd(&lcnt, 1);
                    if (pos < CANDMAX) cand[pos] = i * 4 + j;
                }
            }
        }
        __syncthreads();
        int nc = lcnt < CANDMAX ? lcnt : CANDMAX;
        for (int c = 0; c < nc; ++c) {
            const float* wr = fcw + (size_t)cand[c] * KD;
            float p = 0.f;
            for (int k = tid; k < 1024; k += 256) p += xs[k] * wr[k];
#pragma unroll
            for (int mm = 1; mm < 64; mm <<= 1) p += __shfl_xor(p, mm);
            if (lane == 0) wsum[wv] = p;
            __syncthreads();
            if (tid == 0) cval[c] = wsum[0] + wsum[1] + wsum[2] + wsum[3] + fcb[cand[c]];
            __syncthreads();
        }
        if (tid == 0) {
            float bv = -INFINITY; int bi = 0;
            for (int c = 0; c < nc; ++c) {
                float v = cval[c]; int ii = cand[c];
                if (c == 0 || v > bv || (v == bv && ii < bi)) { bv = v; bi = ii; }
            }
            stok = bi;
            wbuf[b] = 0ull;
        }
    }
    __syncthreads();
    int tok = do_fix ? stok : 0;
    if (tid < 128) {
        const float* er = emb + (size_t)tok * KD + (size_t)tid * 8;
        float4 f0 = ((const float4*)er)[0];
        float4 f1 = ((const float4*)er)[1];
        float ff[8] = {f0.x, f0.y, f0.z, f0.w, f1.x, f1.y, f1.z, f1.w};
        u16x8 h, l;
#pragma unroll
        for (int j = 0; j < 8; ++j) {
            unsigned short hv = f2bf(ff[j]);
            h[j] = hv;
            l[j] = f2bf(ff[j] - bf2f(hv));
        }
        size_t o = (size_t)tid * 256 + (size_t)b * 8;
        *(u16x8*)(xhi + o) = h;
        *(u16x8*)(xlo + o) = l;
    }
}

// ---------------- GRU GEMM: 128 blocks x 384 thr; block=(jt,ks4), wave=panel.
// Depth-4 circular prefetch (fully unrolled -> slots stay in registers).
__global__ __launch_bounds__(384)
void gru_gemm(const unsigned short* __restrict__ xhi, const unsigned short* __restrict__ xlo,
              const unsigned short* __restrict__ hhi, const unsigned short* __restrict__ hlo,
              const unsigned short* __restrict__ wihhi, const unsigned short* __restrict__ wihlo,
              const unsigned short* __restrict__ whhhi, const unsigned short* __restrict__ whhlo,
              float* __restrict__ G)
{
    const int bid = blockIdx.x;
    const int jt = bid >> 2, ks4 = bid & 3;
    const int w = threadIdx.x >> 6, lane = threadIdx.x & 63;
    const int gate = (w < 3) ? w : w - 3;
    const unsigned short* Ah = (w < 3) ? xhi : hhi;
    const unsigned short* Al = (w < 3) ? xlo : hlo;
    const size_t woff = ((size_t)(gate * 32 + jt)) << 15;
    const unsigned short* Wh = ((w < 3) ? wihhi : whhhi) + woff;
    const unsigned short* Wl = ((w < 3) ? wihlo : whhlo) + woff;

    const size_t lo8 = (size_t)lane * 8;
    const int kbase = ks4 * 16;

    f32x16 acc = {0,0,0,0,0,0,0,0,0,0,0,0,0,0,0,0};
    bf16x8 ahB[4], alB[4], whB[4], wlB[4];
#pragma unroll
    for (int i = 0; i < 4; ++i) {
        size_t o = (size_t)(kbase + i) * 512 + lo8;
        ahB[i] = *(const bf16x8*)(Ah + o);
        alB[i] = *(const bf16x8*)(Al + o);
        whB[i] = *(const bf16x8*)(Wh + o);
        wlB[i] = *(const bf16x8*)(Wl + o);
    }
#pragma unroll
    for (int i = 0; i < 16; ++i) {
        const int s = i & 3;
        bf16x8 ah = ahB[s], al = alB[s], wh = whB[s], wl = wlB[s];
        if (i < 12) {
            size_t on = (size_t)(kbase + i + 4) * 512 + lo8;
            ahB[s] = *(const bf16x8*)(Ah + on);
            alB[s] = *(const bf16x8*)(Al + on);
            whB[s] = *(const bf16x8*)(Wh + on);
            wlB[s] = *(const bf16x8*)(Wl + on);
        }
        acc = MF(ah, wh, acc);
        acc = MF(al, wh, acc);
        acc = MF(ah, wl, acc);
    }

    const int kg = lane >> 5, c = lane & 31;
    float* Gb = G + (((size_t)(jt * 4 + ks4) * 6 + w) * B32) * 32;
#pragma unroll
    for (int r = 0; r < 16; ++r) {
        int b = (r & 3) + 8 * (r >> 2) + 4 * kg;
        Gb[b * 32 + c] = acc[r];
    }
}

// ---------------- gates: sum partials, activations, in-place packed h update
__global__ __launch_bounds__(256)
void gru_gates2(const float* __restrict__ G,
                const float* __restrict__ bih, const float* __restrict__ bhh,
                unsigned short* __restrict__ hhi, unsigned short* __restrict__ hlo)
{
    int idx = blockIdx.x * 256 + threadIdx.x;   // 32768
    int b = idx >> 10, j = idx & 1023;
    int jt = j >> 5, c = j & 31;
    float s0 = 0, s1 = 0, s2 = 0, s3 = 0, s4 = 0, s5 = 0;
#pragma unroll
    for (int ks = 0; ks < 4; ++ks) {
        const float* base = G + (((size_t)(jt * 4 + ks) * 6) * B32 + b) * 32 + c;
        s0 += base[0];
        s1 += base[1024];
        s2 += base[2048];
        s3 += base[3072];
        s4 += base[4096];
        s5 += base[5120];
    }
    float rg = sigmoidf_(s0 + bih[j] + s3 + bhh[j]);
    float zg = sigmoidf_(s1 + bih[KD + j] + s4 + bhh[KD + j]);
    float ng = tanhf(s2 + bih[2 * KD + j] + rg * (s5 + bhh[2 * KD + j]));
    size_t hp = (size_t)(j >> 3) * 256 + (size_t)b * 8 + (j & 7);
    float hold = bf2f(hhi[hp]) + bf2f(hlo[hp]);
    float hnew = (1.0f - zg) * ng + zg * hold;
    unsigned short hh = f2bf(hnew);
    hhi[hp] = hh;
    hlo[hp] = f2bf(hnew - bf2f(hh));
}

// ---------------- logits: hi-only W, 250 blocks x 256 thr, wave = one 32-col tile.
// Depth-4 circular prefetch, fully unrolled.
__global__ __launch_bounds__(256)
void logits6(const unsigned short* __restrict__ xh, const unsigned short* __restrict__ xl,
             const unsigned short* __restrict__ wh,
             const float* __restrict__ bias, float* __restrict__ out, int t, int T,
             unsigned long long* __restrict__ wbuf)
{
    __shared__ float bvalS[4][B32];
    __shared__ int   bidxS[4][B32];
    const int tid = threadIdx.x;
    const int w = tid >> 6, lane = tid & 63;
    const int tile = blockIdx.x * 4 + w;
    const int n0 = tile * 32;
    const unsigned short* Wt = wh + ((size_t)tile << 15);
    const size_t lo8 = (size_t)lane * 8;

    f32x16 acc = {0,0,0,0,0,0,0,0,0,0,0,0,0,0,0,0};
    bf16x8 ahB[4], alB[4], wvB[4];
#pragma unroll
    for (int i = 0; i < 4; ++i) {
        size_t o = (size_t)i * 512 + lo8;
        ahB[i] = *(const bf16x8*)(xh + o);
        alB[i] = *(const bf16x8*)(xl + o);
        wvB[i] = *(const bf16x8*)(Wt + o);
    }
#pragma unroll
    for (int i = 0; i < 64; ++i) {
        const int s = i & 3;
        bf16x8 ah = ahB[s], al = alB[s], wv = wvB[s];
        if (i < 60) {
            size_t on = (size_t)(i + 4) * 512 + lo8;
            ahB[s] = *(const bf16x8*)(xh + on);
            alB[s] = *(const bf16x8*)(xl + on);
            wvB[s] = *(const bf16x8*)(Wt + on);
        }
        acc = MF(ah, wv, acc);
        acc = MF(al, wv, acc);
    }

    const int kg = lane >> 5, col = lane & 31;
    const float bb = bias[n0 + col];
#pragma unroll
    for (int r = 0; r < 16; ++r) {
        int b = (r & 3) + 8 * (r >> 2) + 4 * kg;
        float v = acc[r] + bb;
        out[((size_t)b * T + t) * VOC + n0 + col] = v;
        float mv = v; int mi = n0 + col;
#pragma unroll
        for (int m = 1; m < 32; m <<= 1) {
            float ov = __shfl_xor(mv, m);
            int   oi = __shfl_xor(mi, m);
            if (ov > mv || (ov == mv && oi < mi)) { mv = ov; mi = oi; }
        }
        if (col == 0) { bvalS[w][b] = mv; bidxS[w][b] = mi; }
    }
    __syncthreads();
    if (tid < B32) {
        int b = tid;
        float mv = bvalS[0][b]; int mi = bidxS[0][b];
#pragma unroll
        for (int q = 1; q < 4; ++q) {
            float v = bvalS[q][b]; int ii = bidxS[q][b];
            if (v > mv || (v == mv && ii < mi)) { mv = v; mi = ii; }
        }
        unsigned u = __float_as_uint(mv);
        u = (u >> 31) ? ~u : (u | 0x80000000u);
        unsigned long long key =
            ((unsigned long long)u << 32) | (unsigned long long)(0xFFFFFFFFu - (unsigned)mi);
        atomicMax(wbuf + b, key);
    }
}

// ================= fp32 fallback (round-1, proven) =================
__global__ __launch_bounds__(GEMM_THREADS)
void gemm_k1024(const float* __restrict__ Ax, const float* __restrict__ Ah,
                const float* __restrict__ emb, const int* __restrict__ tokens, int gather0,
                const float* __restrict__ Wx, const float* __restrict__ Wh,
                const float* __restrict__ bias,
                float* __restrict__ C, int N, int KS)
{
    __shared__ float As[BKC * ASTR];
    __shared__ float Ws[2 * BKC * WSTR];
    const int tid = threadIdx.x;
    const int sel = blockIdx.y;
    const int ks  = blockIdx.x % KS;
    const int nt  = blockIdx.x / KS;
    const int n0  = nt * TN;
    const int klen = KD / KS;
    const int k0 = ks * klen;
    const float* A = sel ? Ah : Ax;
    const float* W = sel ? Wh : Wx;
    const bool gather = (sel == 0) && (gather0 != 0);

    const int tb = tid & 7;
    const int tn = tid >> 3;
    const int s_kq = tid & 7;
    const int s_r  = tid >> 3;

    const float* arow0;
    const float* arow1;
    if (gather) {
        arow0 = emb + (size_t)tokens[s_r] * KD;
        arow1 = emb + (size_t)tokens[s_r + 16] * KD;
    } else {
        arow0 = A + (size_t)s_r * KD;
        arow1 = A + (size_t)(s_r + 16) * KD;
    }
    const float* wrow = W + (size_t)(n0 + s_r) * KD;

    float acc[4][8];
#pragma unroll
    for (int i = 0; i < 4; ++i)
#pragma unroll
        for (int j = 0; j < 8; ++j) acc[i][j] = 0.0f;

    for (int kc = 0; kc < klen; kc += BKC) {
        const int kb = k0 + kc + s_kq * 4;
        float4 a0 = *(const float4*)(arow0 + kb);
        float4 a1 = *(const float4*)(arow1 + kb);
        float4 wv[8];
#pragma unroll
        for (int hh = 0; hh < 8; ++hh)
            wv[hh] = *(const float4*)(wrow + (size_t)hh * 16 * KD + kb);

        __syncthreads();
#pragma unroll
        for (int j = 0; j < 4; ++j) {
            As[(s_kq * 4 + j) * ASTR + s_r]      = ((const float*)&a0)[j];
            As[(s_kq * 4 + j) * ASTR + s_r + 16] = ((const float*)&a1)[j];
        }
#pragma unroll
        for (int hh = 0; hh < 8; ++hh) {
            int row = s_r + hh * 16;
            int half = row >> 6;
            int c = row & 63;
            float* wbase = &Ws[half * BKC * WSTR];
#pragma unroll
            for (int j = 0; j < 4; ++j)
                wbase[(s_kq * 4 + j) * WSTR + c] = ((const float*)&wv[hh])[j];
        }
        __syncthreads();

#pragma unroll
        for (int kk = 0; kk < BKC; ++kk) {
            float4 av = *(const float4*)&As[kk * ASTR + 4 * tb];
            float4 w0 = *(const float4*)&Ws[kk * WSTR + 4 * tn];
            float4 w1 = *(const float4*)&Ws[BKC * WSTR + kk * WSTR + 4 * tn];
#pragma unroll
            for (int i = 0; i < 4; ++i) {
                float a = ((const float*)&av)[i];
                acc[i][0] += a * w0.x; acc[i][1] += a * w0.y;
                acc[i][2] += a * w0.z; acc[i][3] += a * w0.w;
                acc[i][4] += a * w1.x; acc[i][5] += a * w1.y;
                acc[i][6] += a * w1.z; acc[i][7] += a * w1.w;
            }
        }
    }

    const int slice = sel * KS + ks;
    float* Cb = C + (size_t)slice * B32 * N;
    float4 bA = make_float4(0.f, 0.f, 0.f, 0.f), bB = bA;
    if (bias != nullptr && ks == 0) {
        bA = *(const float4*)&bias[n0 + 4 * tn];
        bB = *(const float4*)&bias[n0 + 64 + 4 * tn];
    }
#pragma unroll
    for (int i = 0; i < 4; ++i) {
        int b = 4 * tb + i;
        float4 vA = make_float4(acc[i][0] + bA.x, acc[i][1] + bA.y, acc[i][2] + bA.z, acc[i][3] + bA.w);
        float4 vB = make_float4(acc[i][4] + bB.x, acc[i][5] + bB.y, acc[i][6] + bB.z, acc[i][7] + bB.w);
        *(float4*)&Cb[(size_t)b * N + n0 + 4 * tn]       = vA;
        *(float4*)&Cb[(size_t)b * N + n0 + 64 + 4 * tn]  = vB;
    }
}

__global__ __launch_bounds__(256)
void gru_gates(const float* __restrict__ G,
               const float* __restrict__ bih, const float* __restrict__ bhh,
               float* __restrict__ hl)
{
    int idx = blockIdx.x * 256 + threadIdx.x;
    int b = idx >> 10, j = idx & 1023;
    float xr = 0, xz = 0, xn = 0, hr = 0, hz = 0, hn = 0;
#pragma unroll
    for (int ks = 0; ks < KS_GRU; ++ks) {
        const float* gx = G + ((size_t)ks * B32 + b) * 3072;
        const float* gh = G + ((size_t)(KS_GRU + ks) * B32 + b) * 3072;
        xr += gx[j];        xz += gx[1024 + j];  xn += gx[2048 + j];
        hr += gh[j];        hz += gh[1024 + j];  hn += gh[2048 + j];
    }
    float r = sigmoidf_(xr + bih[j] + hr + bhh[j]);
    float z = sigmoidf_(xz + bih[1024 + j] + hz + bhh[1024 + j]);
    float n = tanhf(xn + bih[2048 + j] + r * (hn + bhh[2048 + j]));
    float ho = hl[idx];
    hl[idx] = (1.0f - z) * n + z * ho;
}

__global__ __launch_bounds__(GEMM_THREADS)
void logits_kernel(const float* __restrict__ x,
                   const float* __restrict__ W, const float* __restrict__ bias,
                   float* __restrict__ out, int t, int T,
                   float* __restrict__ pval, int* __restrict__ pidx)
{
    __shared__ float As[BKC * ASTR];
    __shared__ float Ws[2 * BKC * WSTR];
    __shared__ float rval[B32 * 16];
    __shared__ int   ridx[B32 * 16];
    const int tid = threadIdx.x;
    const int n0 = blockIdx.x * TN;
    const int tb = tid & 7;
    const int tn = tid >> 3;
    const int s_kq = tid & 7;
    const int s_r  = tid >> 3;

    const float* arow0 = x + (size_t)s_r * KD;
    const float* arow1 = x + (size_t)(s_r + 16) * KD;
    const float* wrow  = W + (size_t)(n0 + s_r) * KD;

    float acc[4][8];
#pragma unroll
    for (int i = 0; i < 4; ++i)
#pragma unroll
        for (int j = 0; j < 8; ++j) acc[i][j] = 0.0f;

    for (int kc = 0; kc < KD; kc += BKC) {
        const int kb = kc + s_kq * 4;
        float4 a0 = *(const float4*)(arow0 + kb);
        float4 a1 = *(const float4*)(arow1 + kb);
        float4 wv[8];
#pragma unroll
        for (int hh = 0; hh < 8; ++hh)
            wv[hh] = *(const float4*)(wrow + (size_t)hh * 16 * KD + kb);

        __syncthreads();
#pragma unroll
        for (int j = 0; j < 4; ++j) {
            As[(s_kq * 4 + j) * ASTR + s_r]      = ((const float*)&a0)[j];
            As[(s_kq * 4 + j) * ASTR + s_r + 16] = ((const float*)&a1)[j];
        }
#pragma unroll
        for (int hh = 0; hh < 8; ++hh) {
            int row = s_r + hh * 16;
            int half = row >> 6;
            int c = row & 63;
            float* wbase = &Ws[half * BKC * WSTR];
#pragma unroll
            for (int j = 0; j < 4; ++j)
                wbase[(s_kq * 4 + j) * WSTR + c] = ((const float*)&wv[hh])[j];
        }
        __syncthreads();

#pragma unroll
        for (int kk = 0; kk < BKC; ++kk) {
            float4 av = *(const float4*)&As[kk * ASTR + 4 * tb];
            float4 w0 = *(const float4*)&Ws[kk * WSTR + 4 * tn];
            float4 w1 = *(const float4*)&Ws[BKC * WSTR + kk * WSTR + 4 * tn];
#pragma unroll
            for (int i = 0; i < 4; ++i) {
                float a = ((const float*)&av)[i];
                acc[i][0] += a * w0.x; acc[i][1] += a * w0.y;
                acc[i][2] += a * w0.z; acc[i][3] += a * w0.w;
                acc[i][4] += a * w1.x; acc[i][5] += a * w1.y;
                acc[i][6] += a * w1.z; acc[i][7] += a * w1.w;
            }
        }
    }

    float4 bA = *(const float4*)&bias[n0 + 4 * tn];
    float4 bB = *(const float4*)&bias[n0 + 64 + 4 * tn];

    float bestv[4]; int besti[4];
#pragma unroll
    for (int i = 0; i < 4; ++i) { bestv[i] = -INFINITY; besti[i] = INT_MAX; }

#pragma unroll
    for (int i = 0; i < 4; ++i) {
        int b = 4 * tb + i;
        float* orow = out + ((size_t)b * T + t) * VOC;
        float4 vA = make_float4(acc[i][0] + bA.x, acc[i][1] + bA.y, acc[i][2] + bA.z, acc[i][3] + bA.w);
        float4 vB = make_float4(acc[i][4] + bB.x, acc[i][5] + bB.y, acc[i][6] + bB.z, acc[i][7] + bB.w);
        *(float4*)&orow[n0 + 4 * tn]      = vA;
        *(float4*)&orow[n0 + 64 + 4 * tn] = vB;
#pragma unroll
        for (int j = 0; j < 4; ++j) {
            float v = ((const float*)&vA)[j]; int c = n0 + 4 * tn + j;
            if (v > bestv[i] || (v == bestv[i] && c < besti[i])) { bestv[i] = v; besti[i] = c; }
        }
#pragma unroll
        for (int j = 0; j < 4; ++j) {
            float v = ((const float*)&vB)[j]; int c = n0 + 64 + 4 * tn + j;
            if (v > bestv[i] || (v == bestv[i] && c < besti[i])) { bestv[i] = v; besti[i] = c; }
        }
    }
#pragma unroll
    for (int i = 0; i < 4; ++i) {
        rval[(4 * tb + i) * 16 + tn] = bestv[i];
        ridx[(4 * tb + i) * 16 + tn] = besti[i];
    }
    __syncthreads();
    if (tid < B32) {
        int b = tid;
        float bv = -INFINITY; int bi = INT_MAX;
        for (int q = 0; q < 16; ++q) {
            float v = rval[b * 16 + q]; int ii = ridx[b * 16 + q];
            if (v > bv || (v == bv && ii < bi)) { bv = v; bi = ii; }
        }
        pval[(size_t)blockIdx.x * B32 + b] = bv;
        pidx[(size_t)blockIdx.x * B32 + b] = bi;
    }
}

__global__ __launch_bounds__(256)
void amax_final(const float* __restrict__ pval, const int* __restrict__ pidx,
                int nblk, int* __restrict__ tokens)
{
    int tid = threadIdx.x;
    int b = tid >> 3, l8 = tid & 7;
    float bv = -INFINITY; int bi = INT_MAX;
    for (int q = l8; q < nblk; q += 8) {
        float v = pval[(size_t)q * B32 + b]; int ii = pidx[(size_t)q * B32 + b];
        if (v > bv || (v == bv && ii < bi)) { bv = v; bi = ii; }
    }
#pragma unroll
    for (int off = 1; off < 8; off <<= 1) {
        float ov = __shfl_xor(bv, off);
        int   oi = __shfl_xor(bi, off);
        if (ov > bv || (ov == bv && oi < bi)) { bv = ov; bi = oi; }
    }
    if (l8 == 0) tokens[b] = bi;
}

// ---------------- host ----------------
extern "C" void kernel_launch(void* const* d_in, const int* in_sizes, int n_in,
                              void* d_out, int out_size, void* d_ws, size_t ws_size,
                              hipStream_t stream)
{
    const float* z    = (const float*)d_in[0];
    const float* emb  = (const float*)d_in[1];
    const float* wlat = (const float*)d_in[2];
    const float* blat = (const float*)d_in[3];
    const float* wih  = (const float*)d_in[4];
    const float* whh  = (const float*)d_in[5];
    const float* bih  = (const float*)d_in[6];
    const float* bhh  = (const float*)d_in[7];
    const float* fcw  = (const float*)d_in[8];
    const float* fcb  = (const float*)d_in[9];
    float* out = (float*)d_out;
    const int T = out_size / (B32 * VOC);   // 128

    const size_t NEED = 152000000;
    if (ws_size >= NEED) {
        char* p = (char*)d_ws;
        auto take = [&](size_t bytes) { char* r = p; p += (bytes + 255) & ~(size_t)255; return r; };
        unsigned short* fcwPh = (unsigned short*)take((size_t)VOC * KD * 2);
        unsigned short* wihPh = (unsigned short*)take((size_t)NL * 3 * KD * KD * 2);
        unsigned short* wihPl = (unsigned short*)take((size_t)NL * 3 * KD * KD * 2);
        unsigned short* whhPh = (unsigned short*)take((size_t)NL * 3 * KD * KD * 2);
        unsigned short* whhPl = (unsigned short*)take((size_t)NL * 3 * KD * KD * 2);
        unsigned short* hPh   = (unsigned short*)take((size_t)NL * B32 * KD * 2);
        unsigned short* hPl   = (unsigned short*)take((size_t)NL * B32 * KD * 2);
        unsigned short* xPh   = (unsigned short*)take((size_t)B32 * KD * 2);
        unsigned short* xPl   = (unsigned short*)take((size_t)B32 * KD * 2);
        float* G   = (float*)take((size_t)32 * 4 * 6 * B32 * 32 * 4);
        float* h32 = (float*)take((size_t)B32 * NL * KD * 4);
        unsigned long long* wbuf = (unsigned long long*)take(B32 * 8);
        unsigned* wn = (unsigned*)take(256);

        hipMemsetAsync(wbuf, 0, B32 * 8, stream);
        hipMemsetAsync(wn, 0, 4, stream);

        // one-time packing (fcw hi-only; GRU weights hi+lo) + column-norm bound
        {
            long nt_fc = VOC / 32;
            long nt_g  = (long)NL * 3 * KD / 32;
            pack_w<<<(unsigned)((nt_fc * 4096 + 255) / 256), 256, 0, stream>>>(fcw, fcwPh, nullptr, nt_fc);
            pack_w<<<(unsigned)((nt_g * 4096 + 255) / 256), 256, 0, stream>>>(wih, wihPh, wihPl, nt_g);
            pack_w<<<(unsigned)((nt_g * 4096 + 255) / 256), 256, 0, stream>>>(whh, whhPh, whhPl, nt_g);
            wnorm_k<<<VOC / 64, 256, 0, stream>>>(fcw, wn);
        }

        // hidden init (fp32), then pack the 3 [32x1024] planes
        gemm_k1024<<<dim3(NL * KD / TN, 1), GEMM_THREADS, 0, stream>>>(
            z, nullptr, nullptr, nullptr, 0, wlat, nullptr, blat, h32, NL * KD, 1);
        pack_w<<<(unsigned)((3L * 4096 + 255) / 256), 256, 0, stream>>>(h32, hPh, hPl, 3);

        const size_t PL = (size_t)B32 * KD;
        for (int t = 0; t < T; ++t) {
            fix_gather<<<B32, 256, 0, stream>>>(
                out, t - 1, T, hPh + 2 * PL, hPl + 2 * PL, fcw, fcb, wn, wbuf,
                emb, xPh, xPl, t > 0 ? 1 : 0);

            for (int l = 0; l < NL; ++l) {
                const unsigned short* xh = (l == 0) ? xPh : hPh + (size_t)(l - 1) * PL;
                const unsigned short* xl = (l == 0) ? xPl : hPl + (size_t)(l - 1) * PL;
                gru_gemm<<<128, 384, 0, stream>>>(
                    xh, xl,
                    hPh + (size_t)l * PL, hPl + (size_t)l * PL,
                    wihPh + (size_t)l * 3 * KD * KD, wihPl + (size_t)l * 3 * KD * KD,
                    whhPh + (size_t)l * 3 * KD * KD, whhPl + (size_t)l * 3 * KD * KD,
                    G);
                gru_gates2<<<128, 256, 0, stream>>>(
                    G, bih + (size_t)l * 3 * KD, bhh + (size_t)l * 3 * KD,
                    hPh + (size_t)l * PL, hPl + (size_t)l * PL);
            }
            logits6<<<250, 256, 0, stream>>>(
                hPh + 2 * PL, hPl + 2 * PL, fcwPh, fcb, out, t, T, wbuf);
        }
    } else {
        // fallback: round-1 fp32 path
        float* h      = (float*)d_ws;
        float* G      = h + (size_t)B32 * NL * HID;
        float* pval   = G + (size_t)2 * KS_GRU * B32 * NL * HID;
        int*   pidx   = (int*)(pval + (VOC / TN) * B32);
        int*   tokens = (int*)(pidx + (VOC / TN) * B32);

        hipMemsetAsync(tokens, 0, B32 * sizeof(int), stream);

        gemm_k1024<<<dim3(NL * HID / TN, 1), GEMM_THREADS, 0, stream>>>(
            z, nullptr, nullptr, nullptr, 0, wlat, nullptr, blat, h, NL * HID, 1);

        for (int t = 0; t < T; ++t) {
            for (int l = 0; l < NL; ++l) {
                const float* xA = (l == 0) ? nullptr : (h + (size_t)(l - 1) * B32 * HID);
                dim3 gg((NL * HID / TN) * KS_GRU, 2);
                gemm_k1024<<<gg, GEMM_THREADS, 0, stream>>>(
                    xA, h + (size_t)l * B32 * HID, emb, tokens, (l == 0) ? 1 : 0,
                    wih + (size_t)l * NL * HID * KD, whh + (size_t)l * NL * HID * KD,
                    nullptr, G, NL * HID, KS_GRU);
                gru_gates<<<B32 * HID / 256, 256, 0, stream>>>(
                    G, bih + (size_t)l * NL * HID, bhh + (size_t)l * NL * HID,
                    h + (size_t)l * B32 * HID);
            }
            logits_kernel<<<VOC / TN, GEMM_THREADS, 0, stream>>>(
                h + (size_t)2 * B32 * HID, fcw, fcb, out, t, T, pval, pidx);
            amax_final<<<1, 256, 0, stream>>>(pval, pidx, VOC / TN, tokens);
        }
    }
}